// Round 5
// baseline (12381.133 us; speedup 1.0000x reference)
//
#include <hip/hip_runtime.h>
#include <cstddef>
#include <cstdint>

#define T256 256

// ---------------- conv1 (1->16, 7x7, relu, maxpool2) ----------------
__global__ __launch_bounds__(256) void conv1_pool_k(
    const float* __restrict__ x, const float* __restrict__ w,
    const float* __restrict__ bias, float* __restrict__ out)
{
  __shared__ float img[10000];
  __shared__ float wsm[16 * 49];
  __shared__ float bsm[16];
  const int b = blockIdx.x, tid = threadIdx.x;
  for (int i = tid; i < 10000; i += T256) img[i] = x[(size_t)b * 10000 + i];
  for (int i = tid; i < 16 * 49; i += T256) wsm[i] = w[i];
  if (tid < 16) bsm[tid] = bias[tid];
  __syncthreads();
  for (int p = tid; p < 47 * 47; p += T256) {
    const int py = p / 47, px = p % 47;
    const int iy0 = 2 * py, ix0 = 2 * px;
    float win[8][8];
#pragma unroll
    for (int r = 0; r < 8; ++r)
#pragma unroll
      for (int c = 0; c < 8; ++c)
        win[r][c] = img[(iy0 + r) * 100 + (ix0 + c)];
#pragma unroll 2
    for (int oc = 0; oc < 16; ++oc) {
      float m = 0.f;
#pragma unroll
      for (int dy = 0; dy < 2; ++dy)
#pragma unroll
        for (int dx = 0; dx < 2; ++dx) {
          float s = bsm[oc];
#pragma unroll
          for (int ky = 0; ky < 7; ++ky)
#pragma unroll
            for (int kx = 0; kx < 7; ++kx)
              s += win[dy + ky][dx + kx] * wsm[oc * 49 + ky * 7 + kx];
          m = fmaxf(m, s);
        }
      out[((size_t)b * 16 + oc) * 2209 + p] = m;
    }
  }
}

// ---------------- generic direct conv (+relu, optional maxpool2) ----------------
// R4: weight rows padded to 16B multiples -> wreg reload via ds_read_b128 (7 vs 25 insts).
template <int IC, int IH, int IW, int K, int POOL, int PL, int OCT>
__global__ __launch_bounds__(256) void convg_k(
    const float* __restrict__ in, const float* __restrict__ w,
    const float* __restrict__ bias, float* __restrict__ out, int OC)
{
  constexpr int OHC = IH - K + 1, OWC = IW - K + 1;
  constexpr int OH = POOL ? OHC / 2 : OHC;
  constexpr int OW = POOL ? OWC / 2 : OWC;
  constexpr int P = OH * OW;
  constexpr int CH = T256 / PL;
  constexpr int G = CH * OCT;
  constexpr int NP = (P + PL - 1) / PL;
  constexpr int WR = POOL ? K + 1 : K;
  constexpr int NCV = POOL ? 2 : 1;
  constexpr int KK = K * K;
  constexpr int KKP = ((KK + 3) / 4) * 4;  // pad rows to float4
  static_assert(CH * PL == 256, "layout");

  __shared__ __align__(16) float plane[IH * IW];
  __shared__ __align__(16) float wsm[G * KKP];
  const int b = blockIdx.x, og = blockIdx.y, tid = threadIdx.x;
  const int pbase = tid % PL, chunk = tid / PL;
  const int ocbase = og * G + chunk * OCT;

  double acc[NP][OCT][NCV * NCV];
#pragma unroll
  for (int a = 0; a < NP; ++a)
#pragma unroll
    for (int o = 0; o < OCT; ++o)
#pragma unroll
      for (int c = 0; c < NCV * NCV; ++c) acc[a][o][c] = 0.0;

  for (int ic = 0; ic < IC; ++ic) {
    __syncthreads();
    for (int i = tid; i < IH * IW; i += T256)
      plane[i] = in[((size_t)b * IC + ic) * (IH * IW) + i];
    for (int i = tid; i < G * KK; i += T256)
      wsm[(i / KK) * KKP + (i % KK)] =
          w[((size_t)(og * G + i / KK) * IC + ic) * KK + i % KK];
    __syncthreads();
    float wreg[OCT][KKP];
#pragma unroll
    for (int o = 0; o < OCT; ++o)
#pragma unroll
      for (int q = 0; q < KKP / 4; ++q) {
        const float4 v = *(const float4*)&wsm[(chunk * OCT + o) * KKP + 4 * q];
        wreg[o][4 * q + 0] = v.x; wreg[o][4 * q + 1] = v.y;
        wreg[o][4 * q + 2] = v.z; wreg[o][4 * q + 3] = v.w;
      }
#pragma unroll
    for (int np = 0; np < NP; ++np) {
      const int p = pbase + np * PL;
      if (P % PL == 0 || p < P) {
        const int py = p / OW, px = p % OW;
        const int iy0 = py * (POOL ? 2 : 1), ix0 = px * (POOL ? 2 : 1);
        float win[WR][WR];
#pragma unroll
        for (int r = 0; r < WR; ++r)
#pragma unroll
          for (int c = 0; c < WR; ++c)
            win[r][c] = plane[(iy0 + r) * IW + (ix0 + c)];
#pragma unroll
        for (int o = 0; o < OCT; ++o)
#pragma unroll
          for (int dy = 0; dy < NCV; ++dy)
#pragma unroll
            for (int dx = 0; dx < NCV; ++dx) {
              float s = 0.f;
#pragma unroll
              for (int ky = 0; ky < K; ++ky)
#pragma unroll
                for (int kx = 0; kx < K; ++kx)
                  s += win[dy + ky][dx + kx] * wreg[o][ky * K + kx];
              acc[np][o][dy * NCV + dx] += (double)s;
            }
      }
    }
  }
#pragma unroll
  for (int np = 0; np < NP; ++np) {
    const int p = pbase + np * PL;
    if (P % PL == 0 || p < P) {
#pragma unroll
      for (int o = 0; o < OCT; ++o) {
        const int oc = ocbase + o;
        double v;
        if constexpr (POOL == 1) {
          double m01 = fmax(acc[np][o][0], acc[np][o][1]);
          double m23 = fmax(acc[np][o][2], acc[np][o][3]);
          v = fmax(m01, m23);
        } else {
          v = acc[np][o][0];
        }
        v = fmax(v + (double)bias[oc], 0.0);
        out[((size_t)b * OC + oc) * P + p] = (float)v;
      }
    }
  }
}

// ---------------- fp32 tiled GEMM (unchanged from R3 PASS) ----------------
template <int ACT>
__global__ __launch_bounds__(256) void gemm_tn_k(
    const float* __restrict__ A, const float* __restrict__ B,
    const float* __restrict__ b1, const float* __restrict__ b2,
    float* __restrict__ C, int M, int N, int K)
{
  __shared__ float As[32][66];
  __shared__ float Bs[32][36];
  const int bn = blockIdx.x, bm = blockIdx.y, tid = threadIdx.x;
  const int tx = tid & 7, ty = tid >> 3;
  const int m0 = bm * 64, n0 = bn * 32;
  double acc[2][4] = {{0, 0, 0, 0}, {0, 0, 0, 0}};
  for (int k0 = 0; k0 < K; k0 += 32) {
    __syncthreads();
#pragma unroll
    for (int l = 0; l < 8; ++l) {
      int id = tid + l * 256;
      int kk = id & 31, mm = id >> 5;
      As[kk][mm] = A[(size_t)(m0 + mm) * K + (k0 + kk)];
    }
#pragma unroll
    for (int l = 0; l < 4; ++l) {
      int id = tid + l * 256;
      int kk = id & 31, nn = id >> 5;
      Bs[kk][nn] = B[(size_t)(n0 + nn) * K + (k0 + kk)];
    }
    __syncthreads();
    float p[2][4] = {{0.f, 0.f, 0.f, 0.f}, {0.f, 0.f, 0.f, 0.f}};
#pragma unroll
    for (int kk = 0; kk < 32; ++kk) {
      const float2 av = *reinterpret_cast<const float2*>(&As[kk][ty * 2]);
      const float4 bv = *reinterpret_cast<const float4*>(&Bs[kk][tx * 4]);
      p[0][0] += av.x * bv.x; p[0][1] += av.x * bv.y;
      p[0][2] += av.x * bv.z; p[0][3] += av.x * bv.w;
      p[1][0] += av.y * bv.x; p[1][1] += av.y * bv.y;
      p[1][2] += av.y * bv.z; p[1][3] += av.y * bv.w;
    }
#pragma unroll
    for (int i = 0; i < 2; ++i)
#pragma unroll
      for (int j = 0; j < 4; ++j) acc[i][j] += (double)p[i][j];
  }
#pragma unroll
  for (int i = 0; i < 2; ++i) {
    const int m = m0 + ty * 2 + i;
#pragma unroll
    for (int j = 0; j < 4; ++j) {
      const int n = n0 + tx * 4 + j;
      double v = acc[i][j] + (double)b1[n];
      if (b2) v += (double)b2[n];
      if (ACT == 1) v = 1.0 / (1.0 + exp(-v));
      C[(size_t)m * N + n] = (float)v;
    }
  }
}

// ---------------- persistent LSTM over 512 steps (R4 rework) ----------------
// 16 WGs x 24 h-cols, 768 threads. 96 gate-rows/WG x 8 lanes; w_hh slice in
// VGPRs (48/thread). h chunks in bank-staggered LDS [8][52], read as b128.
// f32 gates. Barrier: fence + release atomicAdd + tid0 acquire spin (proven R3).
#define NWG 16
#define CPW 24
__global__ __launch_bounds__(768) void lstm_k(
    const float* __restrict__ gin, const float* __restrict__ whh,
    float* __restrict__ out, unsigned int* __restrict__ bar)
{
  __shared__ __align__(16) float hsm[8][52];  // hsm[c][i] = h[c*48+i]; 52-stride staggers banks
  __shared__ float gsum[96];
  const int wg = blockIdx.x, tid = threadIdx.x;
  const int r = tid >> 3, lk = tid & 7;        // 96 rows x 8 lanes
  const int gq = r / CPW, cl = r % CPW;        // gate 0..3, local col
  const int grow = gq * 384 + wg * CPW + cl;   // global gate-row in whh
  float wreg[48];                              // whh[grow][lk*48 .. lk*48+48)
  {
    const float* wr = whh + (size_t)grow * 384 + lk * 48;
#pragma unroll
    for (int i = 0; i < 48; ++i) wreg[i] = wr[i];
  }
  float c = 0.f;  // cell state (threads tid<CPW)
  __syncthreads();
  for (int t = 0; t < 512; ++t) {
    // prefetch gate inputs (independent of h_{t-1})
    float g0 = 0.f, g1 = 0.f, g2 = 0.f, g3 = 0.f;
    if (tid < CPW) {
      const int j = wg * CPW + tid;
      g0 = gin[(size_t)t * 1536 + 0 * 384 + j];
      g1 = gin[(size_t)t * 1536 + 1 * 384 + j];
      g2 = gin[(size_t)t * 1536 + 2 * 384 + j];
      g3 = gin[(size_t)t * 1536 + 3 * 384 + j];
    }
    // stage h_{t-1} into chunked LDS
    if (tid < 384) {
      const float hv = (t == 0) ? 0.f : out[(size_t)(t - 1) * 384 + tid];
      hsm[tid / 48][tid % 48] = hv;
    }
    __syncthreads();
    // 384-dot: lane lk covers h chunk lk (48 elems, 12x ds_read_b128)
    float s = 0.f;
    {
      const float4* hp = (const float4*)&hsm[lk][0];
#pragma unroll
      for (int q = 0; q < 12; ++q) {
        const float4 hv = hp[q];
        s += wreg[4 * q + 0] * hv.x + wreg[4 * q + 1] * hv.y
           + wreg[4 * q + 2] * hv.z + wreg[4 * q + 3] * hv.w;
      }
    }
    s += __shfl_xor(s, 1);
    s += __shfl_xor(s, 2);
    s += __shfl_xor(s, 4);
    if (lk == 0) gsum[r] = s;
    __syncthreads();
    if (tid < CPW) {
      const float gi = gsum[0 * CPW + tid] + g0;
      const float gf = gsum[1 * CPW + tid] + g1;
      const float gg = gsum[2 * CPW + tid] + g2;
      const float go = gsum[3 * CPW + tid] + g3;
      const float si = 1.f / (1.f + expf(-gi));
      const float sf = 1.f / (1.f + expf(-gf));
      const float so = 1.f / (1.f + expf(-go));
      c = sf * c + si * tanhf(gg);
      out[(size_t)t * 384 + wg * CPW + tid] = so * tanhf(c);
    }
    __threadfence();  // release: drain h stores to coherence point
    __syncthreads();
    if (tid == 0) {
      __hip_atomic_fetch_add(bar, 1u, __ATOMIC_RELEASE, __HIP_MEMORY_SCOPE_AGENT);
      const unsigned target = (unsigned)NWG * (unsigned)(t + 1);
      while (__hip_atomic_load(bar, __ATOMIC_ACQUIRE, __HIP_MEMORY_SCOPE_AGENT) < target)
        __builtin_amdgcn_s_sleep(1);
    }
    __syncthreads();
    __threadfence();  // acquire side for all threads before reading remote h
  }
}

extern "C" void kernel_launch(void* const* d_in, const int* in_sizes, int n_in,
                              void* d_out, int out_size, void* d_ws, size_t ws_size,
                              hipStream_t stream)
{
  const float* x   = (const float*)d_in[0];
  const float* cw1 = (const float*)d_in[1];
  const float* cb1 = (const float*)d_in[2];
  const float* cw2 = (const float*)d_in[3];
  const float* cb2 = (const float*)d_in[4];
  const float* cw3 = (const float*)d_in[5];
  const float* cb3 = (const float*)d_in[6];
  const float* cw4 = (const float*)d_in[7];
  const float* cb4 = (const float*)d_in[8];
  const float* cw5 = (const float*)d_in[9];
  const float* cb5 = (const float*)d_in[10];
  const float* cw6 = (const float*)d_in[11];
  const float* cb6 = (const float*)d_in[12];
  const float* lw1 = (const float*)d_in[13];
  const float* lb1 = (const float*)d_in[14];
  const float* lw2 = (const float*)d_in[15];
  const float* lb2 = (const float*)d_in[16];
  const float* wih = (const float*)d_in[17];
  const float* whh = (const float*)d_in[18];
  const float* bih = (const float*)d_in[19];
  const float* bhh = (const float*)d_in[20];
  float* out = (float*)d_out;
  char* ws = (char*)d_ws;

  // workspace layout (fixed in R3; conv1 out = 512*16*2209*4 = 72,384,512 B)
  float* bufA = (float*)(ws);
  float* bufB = (float*)(ws + 72384512);
  float* l1o  = (float*)(ws + 123764736);
  float* x2   = (float*)(ws + 125861888);
  float* gin  = (float*)(ws + 126648320);
  unsigned int* bar = (unsigned int*)(ws + 129794048);

  conv1_pool_k<<<512, 256, 0, stream>>>(x, cw1, cb1, bufA);
  convg_k<16, 47, 47, 4, 1, 256, 4><<<dim3(512, 8), 256, 0, stream>>>(bufA, cw2, cb2, bufB, 32);
  convg_k<32, 22, 22, 5, 0, 128, 4><<<dim3(512, 8), 256, 0, stream>>>(bufB, cw3, cb3, bufA, 64);
  convg_k<64, 18, 18, 5, 0, 64, 4><<<dim3(512, 8), 256, 0, stream>>>(bufA, cw4, cb4, bufB, 128);
  convg_k<128, 14, 14, 5, 0, 32, 4><<<dim3(512, 4), 256, 0, stream>>>(bufB, cw5, cb5, bufA, 128);
  convg_k<128, 10, 10, 3, 0, 32, 4><<<dim3(512, 4), 256, 0, stream>>>(bufA, cw6, cb6, bufB, 128);
  gemm_tn_k<0><<<dim3(1024 / 32, 512 / 64), 256, 0, stream>>>(bufB, lw1, lb1, nullptr, l1o, 512, 1024, 8192);
  gemm_tn_k<1><<<dim3(384 / 32, 512 / 64), 256, 0, stream>>>(l1o, lw2, lb2, nullptr, x2, 512, 384, 1024);
  gemm_tn_k<0><<<dim3(1536 / 32, 512 / 64), 256, 0, stream>>>(x2, wih, bih, bhh, gin, 512, 1536, 384);
  hipMemsetAsync(bar, 0, 256, stream);
  lstm_k<<<NWG, 768, 0, stream>>>(gin, whh, out, bar);
}

// Round 6
// 7231.799 us; speedup vs baseline: 1.7120x; 1.7120x over previous
//
#include <hip/hip_runtime.h>
#include <cstddef>
#include <cstdint>

#define T256 256

// ---------------- conv1 (1->16, 7x7, relu, maxpool2) ----------------
__global__ __launch_bounds__(256) void conv1_pool_k(
    const float* __restrict__ x, const float* __restrict__ w,
    const float* __restrict__ bias, float* __restrict__ out)
{
  __shared__ float img[10000];
  __shared__ float wsm[16 * 49];
  __shared__ float bsm[16];
  const int b = blockIdx.x, tid = threadIdx.x;
  for (int i = tid; i < 10000; i += T256) img[i] = x[(size_t)b * 10000 + i];
  for (int i = tid; i < 16 * 49; i += T256) wsm[i] = w[i];
  if (tid < 16) bsm[tid] = bias[tid];
  __syncthreads();
  for (int p = tid; p < 47 * 47; p += T256) {
    const int py = p / 47, px = p % 47;
    const int iy0 = 2 * py, ix0 = 2 * px;
    float win[8][8];
#pragma unroll
    for (int r = 0; r < 8; ++r)
#pragma unroll
      for (int c = 0; c < 8; ++c)
        win[r][c] = img[(iy0 + r) * 100 + (ix0 + c)];
#pragma unroll 2
    for (int oc = 0; oc < 16; ++oc) {
      float m = 0.f;
#pragma unroll
      for (int dy = 0; dy < 2; ++dy)
#pragma unroll
        for (int dx = 0; dx < 2; ++dx) {
          float s = bsm[oc];
#pragma unroll
          for (int ky = 0; ky < 7; ++ky)
#pragma unroll
            for (int kx = 0; kx < 7; ++kx)
              s += win[dy + ky][dx + kx] * wsm[oc * 49 + ky * 7 + kx];
          m = fmaxf(m, s);
        }
      out[((size_t)b * 16 + oc) * 2209 + p] = m;
    }
  }
}

// ---------------- generic direct conv — R3-PASS form (R4 padding reverted) ----------------
template <int IC, int IH, int IW, int K, int POOL, int PL, int OCT>
__global__ __launch_bounds__(256) void convg_k(
    const float* __restrict__ in, const float* __restrict__ w,
    const float* __restrict__ bias, float* __restrict__ out, int OC)
{
  constexpr int OHC = IH - K + 1, OWC = IW - K + 1;
  constexpr int OH = POOL ? OHC / 2 : OHC;
  constexpr int OW = POOL ? OWC / 2 : OWC;
  constexpr int P = OH * OW;
  constexpr int CH = T256 / PL;
  constexpr int G = CH * OCT;
  constexpr int NP = (P + PL - 1) / PL;
  constexpr int WR = POOL ? K + 1 : K;
  constexpr int NCV = POOL ? 2 : 1;
  static_assert(CH * PL == 256, "layout");

  __shared__ float plane[IH * IW];
  __shared__ float wsm[G * K * K];
  const int b = blockIdx.x, og = blockIdx.y, tid = threadIdx.x;
  const int pbase = tid % PL, chunk = tid / PL;
  const int ocbase = og * G + chunk * OCT;

  double acc[NP][OCT][NCV * NCV];
#pragma unroll
  for (int a = 0; a < NP; ++a)
#pragma unroll
    for (int o = 0; o < OCT; ++o)
#pragma unroll
      for (int c = 0; c < NCV * NCV; ++c) acc[a][o][c] = 0.0;

  for (int ic = 0; ic < IC; ++ic) {
    __syncthreads();
    for (int i = tid; i < IH * IW; i += T256)
      plane[i] = in[((size_t)b * IC + ic) * (IH * IW) + i];
    for (int i = tid; i < G * K * K; i += T256)
      wsm[i] = w[((size_t)(og * G + i / (K * K)) * IC + ic) * (K * K) + i % (K * K)];
    __syncthreads();
    float wreg[OCT][K * K];
#pragma unroll
    for (int o = 0; o < OCT; ++o)
#pragma unroll
      for (int j = 0; j < K * K; ++j)
        wreg[o][j] = wsm[(chunk * OCT + o) * K * K + j];
#pragma unroll
    for (int np = 0; np < NP; ++np) {
      const int p = pbase + np * PL;
      if (P % PL == 0 || p < P) {
        const int py = p / OW, px = p % OW;
        const int iy0 = py * (POOL ? 2 : 1), ix0 = px * (POOL ? 2 : 1);
        float win[WR][WR];
#pragma unroll
        for (int r = 0; r < WR; ++r)
#pragma unroll
          for (int c = 0; c < WR; ++c)
            win[r][c] = plane[(iy0 + r) * IW + (ix0 + c)];
#pragma unroll
        for (int o = 0; o < OCT; ++o)
#pragma unroll
          for (int dy = 0; dy < NCV; ++dy)
#pragma unroll
            for (int dx = 0; dx < NCV; ++dx) {
              float s = 0.f;
#pragma unroll
              for (int ky = 0; ky < K; ++ky)
#pragma unroll
                for (int kx = 0; kx < K; ++kx)
                  s += win[dy + ky][dx + kx] * wreg[o][ky * K + kx];
              acc[np][o][dy * NCV + dx] += (double)s;
            }
      }
    }
  }
#pragma unroll
  for (int np = 0; np < NP; ++np) {
    const int p = pbase + np * PL;
    if (P % PL == 0 || p < P) {
#pragma unroll
      for (int o = 0; o < OCT; ++o) {
        const int oc = ocbase + o;
        double v;
        if constexpr (POOL == 1) {
          double m01 = fmax(acc[np][o][0], acc[np][o][1]);
          double m23 = fmax(acc[np][o][2], acc[np][o][3]);
          v = fmax(m01, m23);
        } else {
          v = acc[np][o][0];
        }
        v = fmax(v + (double)bias[oc], 0.0);
        out[((size_t)b * OC + oc) * P + p] = (float)v;
      }
    }
  }
}

// ---------------- fp32 tiled GEMM (unchanged) ----------------
template <int ACT>
__global__ __launch_bounds__(256) void gemm_tn_k(
    const float* __restrict__ A, const float* __restrict__ B,
    const float* __restrict__ b1, const float* __restrict__ b2,
    float* __restrict__ C, int M, int N, int K)
{
  __shared__ float As[32][66];
  __shared__ float Bs[32][36];
  const int bn = blockIdx.x, bm = blockIdx.y, tid = threadIdx.x;
  const int tx = tid & 7, ty = tid >> 3;
  const int m0 = bm * 64, n0 = bn * 32;
  double acc[2][4] = {{0, 0, 0, 0}, {0, 0, 0, 0}};
  for (int k0 = 0; k0 < K; k0 += 32) {
    __syncthreads();
#pragma unroll
    for (int l = 0; l < 8; ++l) {
      int id = tid + l * 256;
      int kk = id & 31, mm = id >> 5;
      As[kk][mm] = A[(size_t)(m0 + mm) * K + (k0 + kk)];
    }
#pragma unroll
    for (int l = 0; l < 4; ++l) {
      int id = tid + l * 256;
      int kk = id & 31, nn = id >> 5;
      Bs[kk][nn] = B[(size_t)(n0 + nn) * K + (k0 + kk)];
    }
    __syncthreads();
    float p[2][4] = {{0.f, 0.f, 0.f, 0.f}, {0.f, 0.f, 0.f, 0.f}};
#pragma unroll
    for (int kk = 0; kk < 32; ++kk) {
      const float2 av = *reinterpret_cast<const float2*>(&As[kk][ty * 2]);
      const float4 bv = *reinterpret_cast<const float4*>(&Bs[kk][tx * 4]);
      p[0][0] += av.x * bv.x; p[0][1] += av.x * bv.y;
      p[0][2] += av.x * bv.z; p[0][3] += av.x * bv.w;
      p[1][0] += av.y * bv.x; p[1][1] += av.y * bv.y;
      p[1][2] += av.y * bv.z; p[1][3] += av.y * bv.w;
    }
#pragma unroll
    for (int i = 0; i < 2; ++i)
#pragma unroll
      for (int j = 0; j < 4; ++j) acc[i][j] += (double)p[i][j];
  }
#pragma unroll
  for (int i = 0; i < 2; ++i) {
    const int m = m0 + ty * 2 + i;
#pragma unroll
    for (int j = 0; j < 4; ++j) {
      const int n = n0 + tx * 4 + j;
      double v = acc[i][j] + (double)b1[n];
      if (b2) v += (double)b2[n];
      if (ACT == 1) v = 1.0 / (1.0 + exp(-v));
      C[(size_t)m * N + n] = (float)v;
    }
  }
}

// ---------------- persistent LSTM (R5: fence-free, atomics-only exchange) ----------------
// 16 WGs x 24 h-cols, 768 threads; w_hh slice in VGPRs (48/thread).
// ALL cross-WG data moves via agent-scope atomics (LLC-coherent, bypasses
// stale per-XCD L2): h stores/loads relaxed-atomic, counter release/acquire.
// No __threadfence (the R3/R4 8us/step cost). __syncthreads drains vmcnt
// before s_barrier, so h stores are at the coherence point before tid0's bump.
#define NWG 16
#define CPW 24
__global__ __launch_bounds__(768) void lstm_k(
    const float* __restrict__ gin, const float* __restrict__ whh,
    float* __restrict__ out, unsigned int* __restrict__ bar)
{
  __shared__ __align__(16) float hsm[8][52];  // hsm[c][i] = h[c*48+i]
  __shared__ float gsum[96];
  const int wg = blockIdx.x, tid = threadIdx.x;
  const int r = tid >> 3, lk = tid & 7;        // 96 rows x 8 lanes
  const int gq = r / CPW, cl = r % CPW;        // gate 0..3, local col
  const int grow = gq * 384 + wg * CPW + cl;   // global gate-row in whh
  float wreg[48];
  {
    const float* wr = whh + (size_t)grow * 384 + lk * 48;
#pragma unroll
    for (int i = 0; i < 48; ++i) wreg[i] = wr[i];
  }
  float c = 0.f;  // cell state (threads tid<CPW)
  __syncthreads();
  for (int t = 0; t < 512; ++t) {
    // gate-input prefetch (independent of h_{t-1})
    float g0 = 0.f, g1 = 0.f, g2 = 0.f, g3 = 0.f;
    if (tid < CPW) {
      const int j = wg * CPW + tid;
      g0 = gin[(size_t)t * 1536 + 0 * 384 + j];
      g1 = gin[(size_t)t * 1536 + 1 * 384 + j];
      g2 = gin[(size_t)t * 1536 + 2 * 384 + j];
      g3 = gin[(size_t)t * 1536 + 3 * 384 + j];
    }
    // stage h_{t-1}: coherent (agent-scope) loads -> LDS
    if (tid < 384) {
      const float hv = (t == 0) ? 0.f
          : __hip_atomic_load(&out[(size_t)(t - 1) * 384 + tid],
                              __ATOMIC_RELAXED, __HIP_MEMORY_SCOPE_AGENT);
      hsm[tid / 48][tid % 48] = hv;
    }
    __syncthreads();
    // 384-dot: lane lk covers h chunk lk (48 elems, 12x ds_read_b128)
    float s = 0.f;
    {
      const float4* hp = (const float4*)&hsm[lk][0];
#pragma unroll
      for (int q = 0; q < 12; ++q) {
        const float4 hv = hp[q];
        s += wreg[4 * q + 0] * hv.x + wreg[4 * q + 1] * hv.y
           + wreg[4 * q + 2] * hv.z + wreg[4 * q + 3] * hv.w;
      }
    }
    s += __shfl_xor(s, 1);
    s += __shfl_xor(s, 2);
    s += __shfl_xor(s, 4);
    if (lk == 0) gsum[r] = s;
    __syncthreads();
    if (tid < CPW) {
      const float gi = gsum[0 * CPW + tid] + g0;
      const float gf = gsum[1 * CPW + tid] + g1;
      const float gg = gsum[2 * CPW + tid] + g2;
      const float go = gsum[3 * CPW + tid] + g3;
      const float si = 1.f / (1.f + expf(-gi));
      const float sf = 1.f / (1.f + expf(-gf));
      const float so = 1.f / (1.f + expf(-go));
      c = sf * c + si * tanhf(gg);
      __hip_atomic_store(&out[(size_t)t * 384 + wg * CPW + tid], so * tanhf(c),
                         __ATOMIC_RELAXED, __HIP_MEMORY_SCOPE_AGENT);
    }
    __syncthreads();  // drains vmcnt: h stores at coherence point before bump
    if (tid == 0) {
      __hip_atomic_fetch_add(bar, 1u, __ATOMIC_RELEASE, __HIP_MEMORY_SCOPE_AGENT);
      const unsigned target = (unsigned)NWG * (unsigned)(t + 1);
      while (__hip_atomic_load(bar, __ATOMIC_ACQUIRE, __HIP_MEMORY_SCOPE_AGENT) < target)
        __builtin_amdgcn_s_sleep(1);
    }
    __syncthreads();
  }
}

extern "C" void kernel_launch(void* const* d_in, const int* in_sizes, int n_in,
                              void* d_out, int out_size, void* d_ws, size_t ws_size,
                              hipStream_t stream)
{
  const float* x   = (const float*)d_in[0];
  const float* cw1 = (const float*)d_in[1];
  const float* cb1 = (const float*)d_in[2];
  const float* cw2 = (const float*)d_in[3];
  const float* cb2 = (const float*)d_in[4];
  const float* cw3 = (const float*)d_in[5];
  const float* cb3 = (const float*)d_in[6];
  const float* cw4 = (const float*)d_in[7];
  const float* cb4 = (const float*)d_in[8];
  const float* cw5 = (const float*)d_in[9];
  const float* cb5 = (const float*)d_in[10];
  const float* cw6 = (const float*)d_in[11];
  const float* cb6 = (const float*)d_in[12];
  const float* lw1 = (const float*)d_in[13];
  const float* lb1 = (const float*)d_in[14];
  const float* lw2 = (const float*)d_in[15];
  const float* lb2 = (const float*)d_in[16];
  const float* wih = (const float*)d_in[17];
  const float* whh = (const float*)d_in[18];
  const float* bih = (const float*)d_in[19];
  const float* bhh = (const float*)d_in[20];
  float* out = (float*)d_out;
  char* ws = (char*)d_ws;

  // workspace layout (R3 fix; conv1 out = 512*16*2209*4 = 72,384,512 B)
  float* bufA = (float*)(ws);
  float* bufB = (float*)(ws + 72384512);
  float* l1o  = (float*)(ws + 123764736);
  float* x2   = (float*)(ws + 125861888);
  float* gin  = (float*)(ws + 126648320);
  unsigned int* bar = (unsigned int*)(ws + 129794048);

  conv1_pool_k<<<512, 256, 0, stream>>>(x, cw1, cb1, bufA);
  convg_k<16, 47, 47, 4, 1, 256, 4><<<dim3(512, 8), 256, 0, stream>>>(bufA, cw2, cb2, bufB, 32);
  convg_k<32, 22, 22, 5, 0, 128, 4><<<dim3(512, 8), 256, 0, stream>>>(bufB, cw3, cb3, bufA, 64);
  convg_k<64, 18, 18, 5, 0, 64, 4><<<dim3(512, 8), 256, 0, stream>>>(bufA, cw4, cb4, bufB, 128);
  convg_k<128, 14, 14, 5, 0, 32, 4><<<dim3(512, 4), 256, 0, stream>>>(bufB, cw5, cb5, bufA, 128);
  convg_k<128, 10, 10, 3, 0, 32, 4><<<dim3(512, 4), 256, 0, stream>>>(bufA, cw6, cb6, bufB, 128);
  gemm_tn_k<0><<<dim3(1024 / 32, 512 / 64), 256, 0, stream>>>(bufB, lw1, lb1, nullptr, l1o, 512, 1024, 8192);
  gemm_tn_k<1><<<dim3(384 / 32, 512 / 64), 256, 0, stream>>>(l1o, lw2, lb2, nullptr, x2, 512, 384, 1024);
  gemm_tn_k<0><<<dim3(1536 / 32, 512 / 64), 256, 0, stream>>>(x2, wih, bih, bhh, gin, 512, 1536, 384);
  hipMemsetAsync(bar, 0, 256, stream);
  lstm_k<<<NWG, 768, 0, stream>>>(gin, whh, out, bar);
}

// Round 7
// 3196.266 us; speedup vs baseline: 3.8736x; 2.2626x over previous
//
#include <hip/hip_runtime.h>
#include <cstddef>
#include <cstdint>

#define T256 256

typedef __attribute__((ext_vector_type(8))) short bhalf8;
typedef __attribute__((ext_vector_type(4))) float floatx4;

__device__ __forceinline__ ushort f2bf(float f) {
  union { float f; uint32_t u; } v; v.f = f;
  return (ushort)((v.u + 0x7fffu + ((v.u >> 16) & 1u)) >> 16);
}

// ---------------- conv1 (1->16, 7x7, relu, maxpool2) — unchanged R6 PASS ----------------
__global__ __launch_bounds__(256) void conv1_pool_k(
    const float* __restrict__ x, const float* __restrict__ w,
    const float* __restrict__ bias, float* __restrict__ out)
{
  __shared__ float img[10000];
  __shared__ float wsm[16 * 49];
  __shared__ float bsm[16];
  const int b = blockIdx.x, tid = threadIdx.x;
  for (int i = tid; i < 10000; i += T256) img[i] = x[(size_t)b * 10000 + i];
  for (int i = tid; i < 16 * 49; i += T256) wsm[i] = w[i];
  if (tid < 16) bsm[tid] = bias[tid];
  __syncthreads();
  for (int p = tid; p < 47 * 47; p += T256) {
    const int py = p / 47, px = p % 47;
    const int iy0 = 2 * py, ix0 = 2 * px;
    float win[8][8];
#pragma unroll
    for (int r = 0; r < 8; ++r)
#pragma unroll
      for (int c = 0; c < 8; ++c)
        win[r][c] = img[(iy0 + r) * 100 + (ix0 + c)];
#pragma unroll 2
    for (int oc = 0; oc < 16; ++oc) {
      float m = 0.f;
#pragma unroll
      for (int dy = 0; dy < 2; ++dy)
#pragma unroll
        for (int dx = 0; dx < 2; ++dx) {
          float s = bsm[oc];
#pragma unroll
          for (int ky = 0; ky < 7; ++ky)
#pragma unroll
            for (int kx = 0; kx < 7; ++kx)
              s += win[dy + ky][dx + kx] * wsm[oc * 49 + ky * 7 + kx];
          m = fmaxf(m, s);
        }
      out[((size_t)b * 16 + oc) * 2209 + p] = m;
    }
  }
}

// ---------------- generic direct conv (conv2 only now) — unchanged R6 PASS ----------------
template <int IC, int IH, int IW, int K, int POOL, int PL, int OCT>
__global__ __launch_bounds__(256) void convg_k(
    const float* __restrict__ in, const float* __restrict__ w,
    const float* __restrict__ bias, float* __restrict__ out, int OC)
{
  constexpr int OHC = IH - K + 1, OWC = IW - K + 1;
  constexpr int OH = POOL ? OHC / 2 : OHC;
  constexpr int OW = POOL ? OWC / 2 : OWC;
  constexpr int P = OH * OW;
  constexpr int CH = T256 / PL;
  constexpr int G = CH * OCT;
  constexpr int NP = (P + PL - 1) / PL;
  constexpr int WR = POOL ? K + 1 : K;
  constexpr int NCV = POOL ? 2 : 1;
  static_assert(CH * PL == 256, "layout");

  __shared__ float plane[IH * IW];
  __shared__ float wsm[G * K * K];
  const int b = blockIdx.x, og = blockIdx.y, tid = threadIdx.x;
  const int pbase = tid % PL, chunk = tid / PL;
  const int ocbase = og * G + chunk * OCT;

  double acc[NP][OCT][NCV * NCV];
#pragma unroll
  for (int a = 0; a < NP; ++a)
#pragma unroll
    for (int o = 0; o < OCT; ++o)
#pragma unroll
      for (int c = 0; c < NCV * NCV; ++c) acc[a][o][c] = 0.0;

  for (int ic = 0; ic < IC; ++ic) {
    __syncthreads();
    for (int i = tid; i < IH * IW; i += T256)
      plane[i] = in[((size_t)b * IC + ic) * (IH * IW) + i];
    for (int i = tid; i < G * K * K; i += T256)
      wsm[i] = w[((size_t)(og * G + i / (K * K)) * IC + ic) * (K * K) + i % (K * K)];
    __syncthreads();
    float wreg[OCT][K * K];
#pragma unroll
    for (int o = 0; o < OCT; ++o)
#pragma unroll
      for (int j = 0; j < K * K; ++j)
        wreg[o][j] = wsm[(chunk * OCT + o) * K * K + j];
#pragma unroll
    for (int np = 0; np < NP; ++np) {
      const int p = pbase + np * PL;
      if (P % PL == 0 || p < P) {
        const int py = p / OW, px = p % OW;
        const int iy0 = py * (POOL ? 2 : 1), ix0 = px * (POOL ? 2 : 1);
        float win[WR][WR];
#pragma unroll
        for (int r = 0; r < WR; ++r)
#pragma unroll
          for (int c = 0; c < WR; ++c)
            win[r][c] = plane[(iy0 + r) * IW + (ix0 + c)];
#pragma unroll
        for (int o = 0; o < OCT; ++o)
#pragma unroll
          for (int dy = 0; dy < NCV; ++dy)
#pragma unroll
            for (int dx = 0; dx < NCV; ++dx) {
              float s = 0.f;
#pragma unroll
              for (int ky = 0; ky < K; ++ky)
#pragma unroll
                for (int kx = 0; kx < K; ++kx)
                  s += win[dy + ky][dx + kx] * wreg[o][ky * K + kx];
              acc[np][o][dy * NCV + dx] += (double)s;
            }
      }
    }
  }
#pragma unroll
  for (int np = 0; np < NP; ++np) {
    const int p = pbase + np * PL;
    if (P % PL == 0 || p < P) {
#pragma unroll
      for (int o = 0; o < OCT; ++o) {
        const int oc = ocbase + o;
        double v;
        if constexpr (POOL == 1) {
          double m01 = fmax(acc[np][o][0], acc[np][o][1]);
          double m23 = fmax(acc[np][o][2], acc[np][o][3]);
          v = fmax(m01, m23);
        } else {
          v = acc[np][o][0];
        }
        v = fmax(v + (double)bias[oc], 0.0);
        out[((size_t)b * OC + oc) * P + p] = (float)v;
      }
    }
  }
}

// ---------------- weight pre-swizzle for MFMA convs ----------------
// K ordering: k = (ky*KW + kx)*IC + ic. B-frag: lane l supplies col oc=(l&15),
// k = ks*32 + (l>>4)*8 + j (j=0..7, contiguous bf16 -> one 16B load).
// bswz[((ks*NT + nt)*64 + l)*8 + j] = bf16(w[oc][ic][ky][kx]).
__global__ __launch_bounds__(256) void wprep_k(
    const float* __restrict__ w, ushort* __restrict__ bswz,
    int IC, int KW, int OC, int total /* = KS*NT*64 */)
{
  const int idx = blockIdx.x * 256 + threadIdx.x;
  if (idx >= total) return;
  const int NT = OC / 16;
  const int lane = idx & 63;
  const int nt = (idx >> 6) % NT;
  const int ks = idx / (64 * NT);
  const int oc = nt * 16 + (lane & 15);
  const int kb = ks * 32 + (lane >> 4) * 8;
  ushort tmp[8];
#pragma unroll
  for (int j = 0; j < 8; ++j) {
    const int k = kb + j;
    const int ic = k % IC, tap = k / IC;
    tmp[j] = f2bf(w[((size_t)oc * IC + ic) * (KW * KW) + tap]);
  }
  *(bhalf8*)(bswz + (size_t)idx * 8) = *(const bhalf8*)tmp;
}

// ---------------- MFMA implicit-GEMM conv (+bias+relu) ----------------
// Block = 1 image, 4 waves (256t). imgT[pix][ic] bf16 in LDS, row stride
// IC+8 ushorts (+16B pad -> 2-way banks, b128-aligned). A-frag = 1 ds_read_b128
// (K permuted (ky,kx,ic): 8 consecutive k = 8 consecutive ic of one tap).
// B-frag = 1 coalesced global 16B load (prefetched 1 K-step ahead).
template <int IC, int IH, int IW, int KW_, int OC, int MC>
__global__ __launch_bounds__(256) void convmfma_k(
    const float* __restrict__ in, const ushort* __restrict__ bswz,
    const float* __restrict__ bias, float* __restrict__ out)
{
  constexpr int OH = IH - KW_ + 1, OW = IW - KW_ + 1, P = OH * OW;
  constexpr int NPIX = IH * IW;
  constexpr int KS = IC * KW_ * KW_ / 32;   // K-steps of 32
  constexpr int NT = OC / 16;
  constexpr int NPW = NT / 4;               // N-tiles per wave
  constexpr int MT = (P + 15) / 16;         // M-tiles
  constexpr int ROWU = IC + 8;              // ushorts per imgT row
  static_assert(NT % 4 == 0 && IC % 32 == 0, "cfg");

  __shared__ ushort imgT[NPIX * ROWU];
  const int b = blockIdx.x, tid = threadIdx.x;
  const int lane = tid & 63, wv = tid >> 6;
  const int icoff = (lane >> 4) * 8;

  // stage image bf16 pixel-major (coalesced global reads)
  for (int e = tid; e < IC * NPIX; e += 256) {
    const int ic = e / NPIX, pix = e % NPIX;
    imgT[pix * ROWU + ic] = f2bf(in[((size_t)b * IC + ic) * NPIX + pix]);
  }
  __syncthreads();

  for (int m0 = 0; m0 < MT; m0 += MC) {
    floatx4 acc[MC][NPW];
#pragma unroll
    for (int mi = 0; mi < MC; ++mi)
#pragma unroll
      for (int nn = 0; nn < NPW; ++nn)
        acc[mi][nn] = (floatx4){0.f, 0.f, 0.f, 0.f};

    int pbase[MC];  // (input-pixel base)*ROWU for this lane's A-row
#pragma unroll
    for (int mi = 0; mi < MC; ++mi) {
      int p = (m0 + mi) * 16 + (lane & 15);
      p = p < P ? p : P - 1;                 // clamp pad rows
      pbase[mi] = ((p / OW) * IW + (p % OW)) * ROWU;
    }

    bhalf8 bcur[NPW];
#pragma unroll
    for (int nn = 0; nn < NPW; ++nn)
      bcur[nn] = *(const bhalf8*)(bswz + ((size_t)(wv * NPW + nn) * 64 + lane) * 8);

    for (int ks = 0; ks < KS; ++ks) {
      bhalf8 bnext[NPW];
      if (ks + 1 < KS) {
#pragma unroll
        for (int nn = 0; nn < NPW; ++nn)
          bnext[nn] = *(const bhalf8*)(bswz +
              ((size_t)((ks + 1) * NT + wv * NPW + nn) * 64 + lane) * 8);
      }
      const int tap = (ks * 32) / IC;        // uniform per K-step (IC>=32)
      const int icb = (ks * 32) % IC;
      const int aoff = ((tap / KW_) * IW + (tap % KW_)) * ROWU + icb + icoff;
      bhalf8 af[MC];
#pragma unroll
      for (int mi = 0; mi < MC; ++mi)
        af[mi] = *(const bhalf8*)&imgT[pbase[mi] + aoff];
#pragma unroll
      for (int mi = 0; mi < MC; ++mi)
#pragma unroll
        for (int nn = 0; nn < NPW; ++nn)
          acc[mi][nn] = __builtin_amdgcn_mfma_f32_16x16x32_bf16(
              af[mi], bcur[nn], acc[mi][nn], 0, 0, 0);
      if (ks + 1 < KS) {
#pragma unroll
        for (int nn = 0; nn < NPW; ++nn) bcur[nn] = bnext[nn];
      }
    }
    // epilogue: C/D row=(l>>4)*4+i, col=l&15 (m89-verified mapping)
#pragma unroll
    for (int mi = 0; mi < MC; ++mi)
#pragma unroll
      for (int nn = 0; nn < NPW; ++nn) {
        const int oc = (wv * NPW + nn) * 16 + (lane & 15);
#pragma unroll
        for (int i = 0; i < 4; ++i) {
          const int p = (m0 + mi) * 16 + (lane >> 4) * 4 + i;
          if (p < P) {
            const float v = fmaxf(acc[mi][nn][i] + bias[oc], 0.f);
            out[((size_t)b * OC + oc) * P + p] = v;
          }
        }
      }
  }
}

// ---------------- fp32 tiled GEMM — unchanged R6 PASS ----------------
template <int ACT>
__global__ __launch_bounds__(256) void gemm_tn_k(
    const float* __restrict__ A, const float* __restrict__ B,
    const float* __restrict__ b1, const float* __restrict__ b2,
    float* __restrict__ C, int M, int N, int K)
{
  __shared__ float As[32][66];
  __shared__ float Bs[32][36];
  const int bn = blockIdx.x, bm = blockIdx.y, tid = threadIdx.x;
  const int tx = tid & 7, ty = tid >> 3;
  const int m0 = bm * 64, n0 = bn * 32;
  double acc[2][4] = {{0, 0, 0, 0}, {0, 0, 0, 0}};
  for (int k0 = 0; k0 < K; k0 += 32) {
    __syncthreads();
#pragma unroll
    for (int l = 0; l < 8; ++l) {
      int id = tid + l * 256;
      int kk = id & 31, mm = id >> 5;
      As[kk][mm] = A[(size_t)(m0 + mm) * K + (k0 + kk)];
    }
#pragma unroll
    for (int l = 0; l < 4; ++l) {
      int id = tid + l * 256;
      int kk = id & 31, nn = id >> 5;
      Bs[kk][nn] = B[(size_t)(n0 + nn) * K + (k0 + kk)];
    }
    __syncthreads();
    float p[2][4] = {{0.f, 0.f, 0.f, 0.f}, {0.f, 0.f, 0.f, 0.f}};
#pragma unroll
    for (int kk = 0; kk < 32; ++kk) {
      const float2 av = *reinterpret_cast<const float2*>(&As[kk][ty * 2]);
      const float4 bv = *reinterpret_cast<const float4*>(&Bs[kk][tx * 4]);
      p[0][0] += av.x * bv.x; p[0][1] += av.x * bv.y;
      p[0][2] += av.x * bv.z; p[0][3] += av.x * bv.w;
      p[1][0] += av.y * bv.x; p[1][1] += av.y * bv.y;
      p[1][2] += av.y * bv.z; p[1][3] += av.y * bv.w;
    }
#pragma unroll
    for (int i = 0; i < 2; ++i)
#pragma unroll
      for (int j = 0; j < 4; ++j) acc[i][j] += (double)p[i][j];
  }
#pragma unroll
  for (int i = 0; i < 2; ++i) {
    const int m = m0 + ty * 2 + i;
#pragma unroll
    for (int j = 0; j < 4; ++j) {
      const int n = n0 + tx * 4 + j;
      double v = acc[i][j] + (double)b1[n];
      if (b2) v += (double)b2[n];
      if (ACT == 1) v = 1.0 / (1.0 + exp(-v));
      C[(size_t)m * N + n] = (float)v;
    }
  }
}

// ---------------- persistent LSTM — unchanged R6 PASS (fence-free atomics) ----------------
#define NWG 16
#define CPW 24
__global__ __launch_bounds__(768) void lstm_k(
    const float* __restrict__ gin, const float* __restrict__ whh,
    float* __restrict__ out, unsigned int* __restrict__ bar)
{
  __shared__ __align__(16) float hsm[8][52];
  __shared__ float gsum[96];
  const int wg = blockIdx.x, tid = threadIdx.x;
  const int r = tid >> 3, lk = tid & 7;
  const int gq = r / CPW, cl = r % CPW;
  const int grow = gq * 384 + wg * CPW + cl;
  float wreg[48];
  {
    const float* wr = whh + (size_t)grow * 384 + lk * 48;
#pragma unroll
    for (int i = 0; i < 48; ++i) wreg[i] = wr[i];
  }
  float c = 0.f;
  __syncthreads();
  for (int t = 0; t < 512; ++t) {
    float g0 = 0.f, g1 = 0.f, g2 = 0.f, g3 = 0.f;
    if (tid < CPW) {
      const int j = wg * CPW + tid;
      g0 = gin[(size_t)t * 1536 + 0 * 384 + j];
      g1 = gin[(size_t)t * 1536 + 1 * 384 + j];
      g2 = gin[(size_t)t * 1536 + 2 * 384 + j];
      g3 = gin[(size_t)t * 1536 + 3 * 384 + j];
    }
    if (tid < 384) {
      const float hv = (t == 0) ? 0.f
          : __hip_atomic_load(&out[(size_t)(t - 1) * 384 + tid],
                              __ATOMIC_RELAXED, __HIP_MEMORY_SCOPE_AGENT);
      hsm[tid / 48][tid % 48] = hv;
    }
    __syncthreads();
    float s = 0.f;
    {
      const float4* hp = (const float4*)&hsm[lk][0];
#pragma unroll
      for (int q = 0; q < 12; ++q) {
        const float4 hv = hp[q];
        s += wreg[4 * q + 0] * hv.x + wreg[4 * q + 1] * hv.y
           + wreg[4 * q + 2] * hv.z + wreg[4 * q + 3] * hv.w;
      }
    }
    s += __shfl_xor(s, 1);
    s += __shfl_xor(s, 2);
    s += __shfl_xor(s, 4);
    if (lk == 0) gsum[r] = s;
    __syncthreads();
    if (tid < CPW) {
      const float gi = gsum[0 * CPW + tid] + g0;
      const float gf = gsum[1 * CPW + tid] + g1;
      const float gg = gsum[2 * CPW + tid] + g2;
      const float go = gsum[3 * CPW + tid] + g3;
      const float si = 1.f / (1.f + expf(-gi));
      const float sf = 1.f / (1.f + expf(-gf));
      const float so = 1.f / (1.f + expf(-go));
      c = sf * c + si * tanhf(gg);
      __hip_atomic_store(&out[(size_t)t * 384 + wg * CPW + tid], so * tanhf(c),
                         __ATOMIC_RELAXED, __HIP_MEMORY_SCOPE_AGENT);
    }
    __syncthreads();
    if (tid == 0) {
      __hip_atomic_fetch_add(bar, 1u, __ATOMIC_RELEASE, __HIP_MEMORY_SCOPE_AGENT);
      const unsigned target = (unsigned)NWG * (unsigned)(t + 1);
      while (__hip_atomic_load(bar, __ATOMIC_ACQUIRE, __HIP_MEMORY_SCOPE_AGENT) < target)
        __builtin_amdgcn_s_sleep(1);
    }
    __syncthreads();
  }
}

extern "C" void kernel_launch(void* const* d_in, const int* in_sizes, int n_in,
                              void* d_out, int out_size, void* d_ws, size_t ws_size,
                              hipStream_t stream)
{
  const float* x   = (const float*)d_in[0];
  const float* cw1 = (const float*)d_in[1];
  const float* cb1 = (const float*)d_in[2];
  const float* cw2 = (const float*)d_in[3];
  const float* cb2 = (const float*)d_in[4];
  const float* cw3 = (const float*)d_in[5];
  const float* cb3 = (const float*)d_in[6];
  const float* cw4 = (const float*)d_in[7];
  const float* cb4 = (const float*)d_in[8];
  const float* cw5 = (const float*)d_in[9];
  const float* cb5 = (const float*)d_in[10];
  const float* cw6 = (const float*)d_in[11];
  const float* cb6 = (const float*)d_in[12];
  const float* lw1 = (const float*)d_in[13];
  const float* lb1 = (const float*)d_in[14];
  const float* lw2 = (const float*)d_in[15];
  const float* lb2 = (const float*)d_in[16];
  const float* wih = (const float*)d_in[17];
  const float* whh = (const float*)d_in[18];
  const float* bih = (const float*)d_in[19];
  const float* bhh = (const float*)d_in[20];
  float* out = (float*)d_out;
  char* ws = (char*)d_ws;

  // workspace layout (R3-fixed, proven <=129.8 MB)
  float* bufA = (float*)(ws);
  float* bufB = (float*)(ws + 72384512);
  float* l1o  = (float*)(ws + 123764736);   // 2 MB, dead until linear1
  float* x2   = (float*)(ws + 125861888);
  float* gin  = (float*)(ws + 126648320);
  unsigned int* bar = (unsigned int*)(ws + 129794048);
  // swizzled conv weights live inside the (currently-dead) l1o region:
  ushort* bw3 = (ushort*)(ws + 123764736);            // 102,400 B
  ushort* bw4 = (ushort*)(ws + 123764736 + 102400);   // 409,600 B
  ushort* bw5 = (ushort*)(ws + 123764736 + 512000);   // 819,200 B
  ushort* bw6 = (ushort*)(ws + 123764736 + 1331200);  // 294,912 B (ends < l1o+2MB)

  // weight pre-swizzle (reads inputs only; l1o region free until linear1)
  wprep_k<<<(25 * 4 * 64 + 255) / 256, 256, 0, stream>>>(cw3, bw3, 32, 5, 64, 25 * 4 * 64);
  wprep_k<<<(50 * 8 * 64 + 255) / 256, 256, 0, stream>>>(cw4, bw4, 64, 5, 128, 50 * 8 * 64);
  wprep_k<<<(100 * 8 * 64 + 255) / 256, 256, 0, stream>>>(cw5, bw5, 128, 5, 128, 100 * 8 * 64);
  wprep_k<<<(36 * 8 * 64 + 255) / 256, 256, 0, stream>>>(cw6, bw6, 128, 3, 128, 36 * 8 * 64);

  conv1_pool_k<<<512, 256, 0, stream>>>(x, cw1, cb1, bufA);
  convg_k<16, 47, 47, 4, 1, 256, 4><<<dim3(512, 8), 256, 0, stream>>>(bufA, cw2, cb2, bufB, 32);
  // MFMA convs 3-6 (block = 1 image)
  convmfma_k<32, 22, 22, 5, 64, 7><<<512, 256, 0, stream>>>(bufB, bw3, cb3, bufA);
  convmfma_k<64, 18, 18, 5, 128, 7><<<512, 256, 0, stream>>>(bufA, bw4, cb4, bufB);
  convmfma_k<128, 14, 14, 5, 128, 7><<<512, 256, 0, stream>>>(bufB, bw5, cb5, bufA);
  convmfma_k<128, 10, 10, 3, 128, 4><<<512, 256, 0, stream>>>(bufA, bw6, cb6, bufB);

  gemm_tn_k<0><<<dim3(1024 / 32, 512 / 64), 256, 0, stream>>>(bufB, lw1, lb1, nullptr, l1o, 512, 1024, 8192);
  gemm_tn_k<1><<<dim3(384 / 32, 512 / 64), 256, 0, stream>>>(l1o, lw2, lb2, nullptr, x2, 512, 384, 1024);
  gemm_tn_k<0><<<dim3(1536 / 32, 512 / 64), 256, 0, stream>>>(x2, wih, bih, bhh, gin, 512, 1536, 384);
  hipMemsetAsync(bar, 0, 256, stream);
  lstm_k<<<NWG, 768, 0, stream>>>(gin, whh, out, bar);
}

// Round 8
// 2279.435 us; speedup vs baseline: 5.4317x; 1.4022x over previous
//
#include <hip/hip_runtime.h>
#include <cstddef>
#include <cstdint>

#define T256 256

typedef __attribute__((ext_vector_type(8))) short bhalf8;
typedef __attribute__((ext_vector_type(4))) float floatx4;

__device__ __forceinline__ ushort f2bf(float f) {
  union { float f; uint32_t u; } v; v.f = f;
  return (ushort)((v.u + 0x7fffu + ((v.u >> 16) & 1u)) >> 16);
}

// ---------------- conv1 (1->16, 7x7, relu, maxpool2) — unchanged PASS ----------------
__global__ __launch_bounds__(256) void conv1_pool_k(
    const float* __restrict__ x, const float* __restrict__ w,
    const float* __restrict__ bias, float* __restrict__ out)
{
  __shared__ float img[10000];
  __shared__ float wsm[16 * 49];
  __shared__ float bsm[16];
  const int b = blockIdx.x, tid = threadIdx.x;
  for (int i = tid; i < 10000; i += T256) img[i] = x[(size_t)b * 10000 + i];
  for (int i = tid; i < 16 * 49; i += T256) wsm[i] = w[i];
  if (tid < 16) bsm[tid] = bias[tid];
  __syncthreads();
  for (int p = tid; p < 47 * 47; p += T256) {
    const int py = p / 47, px = p % 47;
    const int iy0 = 2 * py, ix0 = 2 * px;
    float win[8][8];
#pragma unroll
    for (int r = 0; r < 8; ++r)
#pragma unroll
      for (int c = 0; c < 8; ++c)
        win[r][c] = img[(iy0 + r) * 100 + (ix0 + c)];
#pragma unroll 2
    for (int oc = 0; oc < 16; ++oc) {
      float m = 0.f;
#pragma unroll
      for (int dy = 0; dy < 2; ++dy)
#pragma unroll
        for (int dx = 0; dx < 2; ++dx) {
          float s = bsm[oc];
#pragma unroll
          for (int ky = 0; ky < 7; ++ky)
#pragma unroll
            for (int kx = 0; kx < 7; ++kx)
              s += win[dy + ky][dx + kx] * wsm[oc * 49 + ky * 7 + kx];
          m = fmaxf(m, s);
        }
      out[((size_t)b * 16 + oc) * 2209 + p] = m;
    }
  }
}

// ---------------- weight pre-swizzle for MFMA convs (proven R7) ----------------
// k = (ky*KW + kx)*IC + ic. B-frag: lane l -> col oc=(l&15), k = ks*32+(l>>4)*8+j.
__global__ __launch_bounds__(256) void wprep_k(
    const float* __restrict__ w, ushort* __restrict__ bswz,
    int IC, int KW, int OC, int total /* = KS*NT*64 */)
{
  const int idx = blockIdx.x * 256 + threadIdx.x;
  if (idx >= total) return;
  const int NT = OC / 16;
  const int lane = idx & 63;
  const int nt = (idx >> 6) % NT;
  const int ks = idx / (64 * NT);
  const int oc = nt * 16 + (lane & 15);
  const int kb = ks * 32 + (lane >> 4) * 8;
  ushort tmp[8];
#pragma unroll
  for (int j = 0; j < 8; ++j) {
    const int k = kb + j;
    const int ic = k % IC, tap = k / IC;
    tmp[j] = f2bf(w[((size_t)oc * IC + ic) * (KW * KW) + tap]);
  }
  *(bhalf8*)(bswz + (size_t)idx * 8) = *(const bhalf8*)tmp;
}

// ---------------- conv2 MFMA with in-register 2x2 maxpool ----------------
// (512,16,47,47) -> conv4x4 (44x44) -> relu -> pool -> (512,32,22,22).
// Block = 1 image, 4 waves splitting (pyp,tx) space. Conv rows padded 44->48
// = 3 M-tiles/row so each tile has uniform py, lane rows = 4 consecutive px.
// One iteration = vertical tile pair (rows 2pyp, 2pyp+1): vmax across the two
// accs, hmax across in-lane reg pairs -> pooled store. 9% pad waste.
__global__ __launch_bounds__(256) void conv2mfma_k(
    const float* __restrict__ in, const ushort* __restrict__ bswz,
    const float* __restrict__ bias, float* __restrict__ out)
{
  constexpr int IC = 16, IH = 47, IW = 47;
  constexpr int NPIX = IH * IW;          // 2209
  constexpr int ROWU = IC + 8;           // 24 ushorts = 48 B (b128-aligned rows)
  constexpr int KS = 8;                  // K = 16ic*16taps = 256
  __shared__ ushort imgT[NPIX * ROWU];   // 106 KB
  const int b = blockIdx.x, tid = threadIdx.x;
  const int lane = tid & 63, wv = tid >> 6;

  for (int e = tid; e < IC * NPIX; e += 256) {
    const int ic = e / NPIX, pix = e % NPIX;
    imgT[pix * ROWU + ic] = f2bf(in[((size_t)b * IC + ic) * NPIX + pix]);
  }
  __syncthreads();

  const int col = lane & 15, g = lane >> 4;
  const float b0 = bias[col], b1 = bias[16 + col];

  for (int it = wv; it < 66; it += 4) {     // 22 pyp x 3 tx
    const int pyp = it / 3, tx = it - pyp * 3;
    int px = tx * 16 + col; px = px < 43 ? px : 43;   // clamp pad cols
    floatx4 acc[2][2];
#pragma unroll
    for (int dy = 0; dy < 2; ++dy)
#pragma unroll
      for (int nt = 0; nt < 2; ++nt) acc[dy][nt] = (floatx4){0.f, 0.f, 0.f, 0.f};

    for (int ks = 0; ks < KS; ++ks) {
      bhalf8 bf[2];
#pragma unroll
      for (int nt = 0; nt < 2; ++nt)
        bf[nt] = *(const bhalf8*)(bswz + ((size_t)(ks * 2 + nt) * 64 + lane) * 8);
      const int kk = ks * 32 + g * 8;
      const int tap = kk >> 4, icb = kk & 15;         // tap uniform per lane-group
      const int ky = tap >> 2, kx = tap & 3;
      bhalf8 af[2];
#pragma unroll
      for (int dy = 0; dy < 2; ++dy)
        af[dy] = *(const bhalf8*)&imgT[((2 * pyp + dy + ky) * IW + px + kx) * ROWU + icb];
#pragma unroll
      for (int dy = 0; dy < 2; ++dy)
#pragma unroll
        for (int nt = 0; nt < 2; ++nt)
          acc[dy][nt] = __builtin_amdgcn_mfma_f32_16x16x32_bf16(
              af[dy], bf[nt], acc[dy][nt], 0, 0, 0);
    }
    // pooled epilogue: rows of tile = px = tx*16 + g*4 + i
#pragma unroll
    for (int nt = 0; nt < 2; ++nt) {
      const int oc = nt * 16 + col;
      const float bb = nt ? b1 : b0;
      float vv[4];
#pragma unroll
      for (int i = 0; i < 4; ++i) vv[i] = fmaxf(acc[0][nt][i], acc[1][nt][i]);
#pragma unroll
      for (int q = 0; q < 2; ++q) {
        const int pxp = tx * 8 + g * 2 + q;
        if (pxp < 22) {
          const float v = fmaxf(fmaxf(vv[2 * q], vv[2 * q + 1]) + bb, 0.f);
          out[((size_t)b * 32 + oc) * 484 + pyp * 22 + pxp] = v;
        }
      }
    }
  }
}

// ---------------- MFMA implicit-GEMM conv (+bias+relu) — unchanged R7 PASS ----------------
template <int IC, int IH, int IW, int KW_, int OC, int MC>
__global__ __launch_bounds__(256) void convmfma_k(
    const float* __restrict__ in, const ushort* __restrict__ bswz,
    const float* __restrict__ bias, float* __restrict__ out)
{
  constexpr int OH = IH - KW_ + 1, OW = IW - KW_ + 1, P = OH * OW;
  constexpr int NPIX = IH * IW;
  constexpr int KS = IC * KW_ * KW_ / 32;
  constexpr int NT = OC / 16;
  constexpr int NPW = NT / 4;
  constexpr int MT = (P + 15) / 16;
  constexpr int ROWU = IC + 8;
  static_assert(NT % 4 == 0 && IC % 32 == 0, "cfg");

  __shared__ ushort imgT[NPIX * ROWU];
  const int b = blockIdx.x, tid = threadIdx.x;
  const int lane = tid & 63, wv = tid >> 6;
  const int icoff = (lane >> 4) * 8;

  for (int e = tid; e < IC * NPIX; e += 256) {
    const int ic = e / NPIX, pix = e % NPIX;
    imgT[pix * ROWU + ic] = f2bf(in[((size_t)b * IC + ic) * NPIX + pix]);
  }
  __syncthreads();

  for (int m0 = 0; m0 < MT; m0 += MC) {
    floatx4 acc[MC][NPW];
#pragma unroll
    for (int mi = 0; mi < MC; ++mi)
#pragma unroll
      for (int nn = 0; nn < NPW; ++nn)
        acc[mi][nn] = (floatx4){0.f, 0.f, 0.f, 0.f};

    int pbase[MC];
#pragma unroll
    for (int mi = 0; mi < MC; ++mi) {
      int p = (m0 + mi) * 16 + (lane & 15);
      p = p < P ? p : P - 1;
      pbase[mi] = ((p / OW) * IW + (p % OW)) * ROWU;
    }

    bhalf8 bcur[NPW];
#pragma unroll
    for (int nn = 0; nn < NPW; ++nn)
      bcur[nn] = *(const bhalf8*)(bswz + ((size_t)(wv * NPW + nn) * 64 + lane) * 8);

    for (int ks = 0; ks < KS; ++ks) {
      bhalf8 bnext[NPW];
      if (ks + 1 < KS) {
#pragma unroll
        for (int nn = 0; nn < NPW; ++nn)
          bnext[nn] = *(const bhalf8*)(bswz +
              ((size_t)((ks + 1) * NT + wv * NPW + nn) * 64 + lane) * 8);
      }
      const int tap = (ks * 32) / IC;
      const int icb = (ks * 32) % IC;
      const int aoff = ((tap / KW_) * IW + (tap % KW_)) * ROWU + icb + icoff;
      bhalf8 af[MC];
#pragma unroll
      for (int mi = 0; mi < MC; ++mi)
        af[mi] = *(const bhalf8*)&imgT[pbase[mi] + aoff];
#pragma unroll
      for (int mi = 0; mi < MC; ++mi)
#pragma unroll
        for (int nn = 0; nn < NPW; ++nn)
          acc[mi][nn] = __builtin_amdgcn_mfma_f32_16x16x32_bf16(
              af[mi], bcur[nn], acc[mi][nn], 0, 0, 0);
      if (ks + 1 < KS) {
#pragma unroll
        for (int nn = 0; nn < NPW; ++nn) bcur[nn] = bnext[nn];
      }
    }
#pragma unroll
    for (int mi = 0; mi < MC; ++mi)
#pragma unroll
      for (int nn = 0; nn < NPW; ++nn) {
        const int oc = (wv * NPW + nn) * 16 + (lane & 15);
#pragma unroll
        for (int i = 0; i < 4; ++i) {
          const int p = (m0 + mi) * 16 + (lane >> 4) * 4 + i;
          if (p < P) {
            const float v = fmaxf(acc[mi][nn][i] + bias[oc], 0.f);
            out[((size_t)b * OC + oc) * P + p] = v;
          }
        }
      }
  }
}

// ---------------- fp32 tiled GEMM — unchanged PASS ----------------
template <int ACT>
__global__ __launch_bounds__(256) void gemm_tn_k(
    const float* __restrict__ A, const float* __restrict__ B,
    const float* __restrict__ b1, const float* __restrict__ b2,
    float* __restrict__ C, int M, int N, int K)
{
  __shared__ float As[32][66];
  __shared__ float Bs[32][36];
  const int bn = blockIdx.x, bm = blockIdx.y, tid = threadIdx.x;
  const int tx = tid & 7, ty = tid >> 3;
  const int m0 = bm * 64, n0 = bn * 32;
  double acc[2][4] = {{0, 0, 0, 0}, {0, 0, 0, 0}};
  for (int k0 = 0; k0 < K; k0 += 32) {
    __syncthreads();
#pragma unroll
    for (int l = 0; l < 8; ++l) {
      int id = tid + l * 256;
      int kk = id & 31, mm = id >> 5;
      As[kk][mm] = A[(size_t)(m0 + mm) * K + (k0 + kk)];
    }
#pragma unroll
    for (int l = 0; l < 4; ++l) {
      int id = tid + l * 256;
      int kk = id & 31, nn = id >> 5;
      Bs[kk][nn] = B[(size_t)(n0 + nn) * K + (k0 + kk)];
    }
    __syncthreads();
    float p[2][4] = {{0.f, 0.f, 0.f, 0.f}, {0.f, 0.f, 0.f, 0.f}};
#pragma unroll
    for (int kk = 0; kk < 32; ++kk) {
      const float2 av = *reinterpret_cast<const float2*>(&As[kk][ty * 2]);
      const float4 bv = *reinterpret_cast<const float4*>(&Bs[kk][tx * 4]);
      p[0][0] += av.x * bv.x; p[0][1] += av.x * bv.y;
      p[0][2] += av.x * bv.z; p[0][3] += av.x * bv.w;
      p[1][0] += av.y * bv.x; p[1][1] += av.y * bv.y;
      p[1][2] += av.y * bv.z; p[1][3] += av.y * bv.w;
    }
#pragma unroll
    for (int i = 0; i < 2; ++i)
#pragma unroll
      for (int j = 0; j < 4; ++j) acc[i][j] += (double)p[i][j];
  }
#pragma unroll
  for (int i = 0; i < 2; ++i) {
    const int m = m0 + ty * 2 + i;
#pragma unroll
    for (int j = 0; j < 4; ++j) {
      const int n = n0 + tx * 4 + j;
      double v = acc[i][j] + (double)b1[n];
      if (b2) v += (double)b2[n];
      if (ACT == 1) v = 1.0 / (1.0 + exp(-v));
      C[(size_t)m * N + n] = (float)v;
    }
  }
}

// ---------------- persistent LSTM (R8: flag-broadcast barrier, no RMW) ----------------
// Per step: after __syncthreads (vmcnt drained -> h stores at LLC), each WG
// release-stores flags[wg]=t+1 on its OWN cacheline; threads tid<16 acquire-
// spin on all 16 flags IN PARALLEL (replaces 16 serialized atomicAdds).
#define NWG 16
#define CPW 24
__global__ __launch_bounds__(768) void lstm_k(
    const float* __restrict__ gin, const float* __restrict__ whh,
    float* __restrict__ out, unsigned int* __restrict__ flags)
{
  __shared__ __align__(16) float hsm[8][52];
  __shared__ float gsum[96];
  const int wg = blockIdx.x, tid = threadIdx.x;
  const int r = tid >> 3, lk = tid & 7;
  const int gq = r / CPW, cl = r % CPW;
  const int grow = gq * 384 + wg * CPW + cl;
  float wreg[48];
  {
    const float* wr = whh + (size_t)grow * 384 + lk * 48;
#pragma unroll
    for (int i = 0; i < 48; ++i) wreg[i] = wr[i];
  }
  float c = 0.f;
  __syncthreads();
  for (int t = 0; t < 512; ++t) {
    float g0 = 0.f, g1 = 0.f, g2 = 0.f, g3 = 0.f;
    if (tid < CPW) {
      const int j = wg * CPW + tid;
      g0 = gin[(size_t)t * 1536 + 0 * 384 + j];
      g1 = gin[(size_t)t * 1536 + 1 * 384 + j];
      g2 = gin[(size_t)t * 1536 + 2 * 384 + j];
      g3 = gin[(size_t)t * 1536 + 3 * 384 + j];
    }
    if (tid < 384) {
      const float hv = (t == 0) ? 0.f
          : __hip_atomic_load(&out[(size_t)(t - 1) * 384 + tid],
                              __ATOMIC_RELAXED, __HIP_MEMORY_SCOPE_AGENT);
      hsm[tid / 48][tid % 48] = hv;
    }
    __syncthreads();
    float s = 0.f;
    {
      const float4* hp = (const float4*)&hsm[lk][0];
#pragma unroll
      for (int q = 0; q < 12; ++q) {
        const float4 hv = hp[q];
        s += wreg[4 * q + 0] * hv.x + wreg[4 * q + 1] * hv.y
           + wreg[4 * q + 2] * hv.z + wreg[4 * q + 3] * hv.w;
      }
    }
    s += __shfl_xor(s, 1);
    s += __shfl_xor(s, 2);
    s += __shfl_xor(s, 4);
    if (lk == 0) gsum[r] = s;
    __syncthreads();
    if (tid < CPW) {
      const float gi = gsum[0 * CPW + tid] + g0;
      const float gf = gsum[1 * CPW + tid] + g1;
      const float gg = gsum[2 * CPW + tid] + g2;
      const float go = gsum[3 * CPW + tid] + g3;
      const float si = 1.f / (1.f + expf(-gi));
      const float sf = 1.f / (1.f + expf(-gf));
      const float so = 1.f / (1.f + expf(-go));
      c = sf * c + si * tanhf(gg);
      __hip_atomic_store(&out[(size_t)t * 384 + wg * CPW + tid], so * tanhf(c),
                         __ATOMIC_RELAXED, __HIP_MEMORY_SCOPE_AGENT);
    }
    __syncthreads();  // drains vmcnt: h stores at coherence point
    if (tid == 0)
      __hip_atomic_store(&flags[wg * 32], (unsigned)(t + 1),
                         __ATOMIC_RELEASE, __HIP_MEMORY_SCOPE_AGENT);
    if (tid < NWG) {
      while (__hip_atomic_load(&flags[tid * 32],
                               __ATOMIC_ACQUIRE, __HIP_MEMORY_SCOPE_AGENT)
             < (unsigned)(t + 1)) { }
    }
    __syncthreads();
  }
}

extern "C" void kernel_launch(void* const* d_in, const int* in_sizes, int n_in,
                              void* d_out, int out_size, void* d_ws, size_t ws_size,
                              hipStream_t stream)
{
  const float* x   = (const float*)d_in[0];
  const float* cw1 = (const float*)d_in[1];
  const float* cb1 = (const float*)d_in[2];
  const float* cw2 = (const float*)d_in[3];
  const float* cb2 = (const float*)d_in[4];
  const float* cw3 = (const float*)d_in[5];
  const float* cb3 = (const float*)d_in[6];
  const float* cw4 = (const float*)d_in[7];
  const float* cb4 = (const float*)d_in[8];
  const float* cw5 = (const float*)d_in[9];
  const float* cb5 = (const float*)d_in[10];
  const float* cw6 = (const float*)d_in[11];
  const float* cb6 = (const float*)d_in[12];
  const float* lw1 = (const float*)d_in[13];
  const float* lb1 = (const float*)d_in[14];
  const float* lw2 = (const float*)d_in[15];
  const float* lb2 = (const float*)d_in[16];
  const float* wih = (const float*)d_in[17];
  const float* whh = (const float*)d_in[18];
  const float* bih = (const float*)d_in[19];
  const float* bhh = (const float*)d_in[20];
  float* out = (float*)d_out;
  char* ws = (char*)d_ws;

  // workspace layout (R3-fixed, proven)
  float* bufA = (float*)(ws);
  float* bufB = (float*)(ws + 72384512);
  float* l1o  = (float*)(ws + 123764736);   // 2 MB, dead until linear1
  float* x2   = (float*)(ws + 125861888);
  float* gin  = (float*)(ws + 126648320);
  unsigned int* flags = (unsigned int*)(ws + 129794048);  // 16 x 128B cachelines
  // swizzled conv weights inside the (currently-dead) l1o region:
  ushort* bw3 = (ushort*)(ws + 123764736);            // 102,400 B
  ushort* bw4 = (ushort*)(ws + 123764736 + 102400);   // 409,600 B
  ushort* bw5 = (ushort*)(ws + 123764736 + 512000);   // 819,200 B
  ushort* bw6 = (ushort*)(ws + 123764736 + 1331200);  // 294,912 B
  ushort* bw2 = (ushort*)(ws + 123764736 + 1626112);  // 16,384 B (ends < l1o+2MB)

  // weight pre-swizzle (reads inputs only; l1o free until linear1)
  wprep_k<<<(25 * 4 * 64 + 255) / 256, 256, 0, stream>>>(cw3, bw3, 32, 5, 64, 25 * 4 * 64);
  wprep_k<<<(50 * 8 * 64 + 255) / 256, 256, 0, stream>>>(cw4, bw4, 64, 5, 128, 50 * 8 * 64);
  wprep_k<<<(100 * 8 * 64 + 255) / 256, 256, 0, stream>>>(cw5, bw5, 128, 5, 128, 100 * 8 * 64);
  wprep_k<<<(36 * 8 * 64 + 255) / 256, 256, 0, stream>>>(cw6, bw6, 128, 3, 128, 36 * 8 * 64);
  wprep_k<<<(8 * 2 * 64 + 255) / 256, 256, 0, stream>>>(cw2, bw2, 16, 4, 32, 8 * 2 * 64);

  conv1_pool_k<<<512, 256, 0, stream>>>(x, cw1, cb1, bufA);
  conv2mfma_k<<<512, 256, 0, stream>>>(bufA, bw2, cb2, bufB);
  convmfma_k<32, 22, 22, 5, 64, 7><<<512, 256, 0, stream>>>(bufB, bw3, cb3, bufA);
  convmfma_k<64, 18, 18, 5, 128, 7><<<512, 256, 0, stream>>>(bufA, bw4, cb4, bufB);
  convmfma_k<128, 14, 14, 5, 128, 7><<<512, 256, 0, stream>>>(bufB, bw5, cb5, bufA);
  convmfma_k<128, 10, 10, 3, 128, 4><<<512, 256, 0, stream>>>(bufA, bw6, cb6, bufB);

  gemm_tn_k<0><<<dim3(1024 / 32, 512 / 64), 256, 0, stream>>>(bufB, lw1, lb1, nullptr, l1o, 512, 1024, 8192);
  gemm_tn_k<1><<<dim3(384 / 32, 512 / 64), 256, 0, stream>>>(l1o, lw2, lb2, nullptr, x2, 512, 384, 1024);
  gemm_tn_k<0><<<dim3(1536 / 32, 512 / 64), 256, 0, stream>>>(x2, wih, bih, bhh, gin, 512, 1536, 384);
  hipMemsetAsync(flags, 0, 2048, stream);
  lstm_k<<<NWG, 768, 0, stream>>>(gin, whh, out, flags);
}

// Round 9
// 1597.442 us; speedup vs baseline: 7.7506x; 1.4269x over previous
//
#include <hip/hip_runtime.h>
#include <cstddef>
#include <cstdint>

#define T256 256

typedef __attribute__((ext_vector_type(8))) short bhalf8;
typedef __attribute__((ext_vector_type(4))) float floatx4;

__device__ __forceinline__ ushort f2bf(float f) {
  union { float f; uint32_t u; } v; v.f = f;
  return (ushort)((v.u + 0x7fffu + ((v.u >> 16) & 1u)) >> 16);
}

// ---------------- conv1 (1->16, 7x7, relu, maxpool2) — unchanged PASS ----------------
__global__ __launch_bounds__(256) void conv1_pool_k(
    const float* __restrict__ x, const float* __restrict__ w,
    const float* __restrict__ bias, float* __restrict__ out)
{
  __shared__ float img[10000];
  __shared__ float wsm[16 * 49];
  __shared__ float bsm[16];
  const int b = blockIdx.x, tid = threadIdx.x;
  for (int i = tid; i < 10000; i += T256) img[i] = x[(size_t)b * 10000 + i];
  for (int i = tid; i < 16 * 49; i += T256) wsm[i] = w[i];
  if (tid < 16) bsm[tid] = bias[tid];
  __syncthreads();
  for (int p = tid; p < 47 * 47; p += T256) {
    const int py = p / 47, px = p % 47;
    const int iy0 = 2 * py, ix0 = 2 * px;
    float win[8][8];
#pragma unroll
    for (int r = 0; r < 8; ++r)
#pragma unroll
      for (int c = 0; c < 8; ++c)
        win[r][c] = img[(iy0 + r) * 100 + (ix0 + c)];
#pragma unroll 2
    for (int oc = 0; oc < 16; ++oc) {
      float m = 0.f;
#pragma unroll
      for (int dy = 0; dy < 2; ++dy)
#pragma unroll
        for (int dx = 0; dx < 2; ++dx) {
          float s = bsm[oc];
#pragma unroll
          for (int ky = 0; ky < 7; ++ky)
#pragma unroll
            for (int kx = 0; kx < 7; ++kx)
              s += win[dy + ky][dx + kx] * wsm[oc * 49 + ky * 7 + kx];
          m = fmaxf(m, s);
        }
      out[((size_t)b * 16 + oc) * 2209 + p] = m;
    }
  }
}

// ---------------- weight pre-swizzle for MFMA convs (proven) ----------------
__global__ __launch_bounds__(256) void wprep_k(
    const float* __restrict__ w, ushort* __restrict__ bswz,
    int IC, int KW, int OC, int total)
{
  const int idx = blockIdx.x * 256 + threadIdx.x;
  if (idx >= total) return;
  const int NT = OC / 16;
  const int lane = idx & 63;
  const int nt = (idx >> 6) % NT;
  const int ks = idx / (64 * NT);
  const int oc = nt * 16 + (lane & 15);
  const int kb = ks * 32 + (lane >> 4) * 8;
  ushort tmp[8];
#pragma unroll
  for (int j = 0; j < 8; ++j) {
    const int k = kb + j;
    const int ic = k % IC, tap = k / IC;
    tmp[j] = f2bf(w[((size_t)oc * IC + ic) * (KW * KW) + tap]);
  }
  *(bhalf8*)(bswz + (size_t)idx * 8) = *(const bhalf8*)tmp;
}

// ---------------- linear-weight pre-swizzle (B[n][k] = w[n][k], k plain) ----------------
__global__ __launch_bounds__(256) void wprep_lin_k(
    const float* __restrict__ w, ushort* __restrict__ bswz,
    int Kdim, int NT, int total)
{
  const int idx = blockIdx.x * 256 + threadIdx.x;
  if (idx >= total) return;
  const int lane = idx & 63;
  const int nt = (idx >> 6) % NT;
  const int ks = idx / (64 * NT);
  const int oc = nt * 16 + (lane & 15);
  const int kb = ks * 32 + (lane >> 4) * 8;
  ushort tmp[8];
#pragma unroll
  for (int j = 0; j < 8; ++j) tmp[j] = f2bf(w[(size_t)oc * Kdim + kb + j]);
  *(bhalf8*)(bswz + (size_t)idx * 8) = *(const bhalf8*)tmp;
}

// ---------------- f32 -> bf16 convert (n divisible by 4) ----------------
__global__ __launch_bounds__(256) void f2bf_k(
    const float* __restrict__ in, ushort* __restrict__ outv, int n)
{
  const int i = (blockIdx.x * 256 + threadIdx.x) * 4;
  if (i >= n) return;
  const float4 v = *(const float4*)&in[i];
  ushort tmp[4] = {f2bf(v.x), f2bf(v.y), f2bf(v.z), f2bf(v.w)};
  *(uint2*)&outv[i] = *(const uint2*)tmp;
}

// ---------------- conv2 MFMA with in-register 2x2 maxpool — unchanged PASS ----------------
__global__ __launch_bounds__(256) void conv2mfma_k(
    const float* __restrict__ in, const ushort* __restrict__ bswz,
    const float* __restrict__ bias, float* __restrict__ out)
{
  constexpr int IC = 16, IH = 47, IW = 47;
  constexpr int NPIX = IH * IW;
  constexpr int ROWU = IC + 8;
  constexpr int KS = 8;
  __shared__ ushort imgT[NPIX * ROWU];
  const int b = blockIdx.x, tid = threadIdx.x;
  const int lane = tid & 63, wv = tid >> 6;

  for (int e = tid; e < IC * NPIX; e += 256) {
    const int ic = e / NPIX, pix = e % NPIX;
    imgT[pix * ROWU + ic] = f2bf(in[((size_t)b * IC + ic) * NPIX + pix]);
  }
  __syncthreads();

  const int col = lane & 15, g = lane >> 4;
  const float b0 = bias[col], b1 = bias[16 + col];

  for (int it = wv; it < 66; it += 4) {
    const int pyp = it / 3, tx = it - pyp * 3;
    int px = tx * 16 + col; px = px < 43 ? px : 43;
    floatx4 acc[2][2];
#pragma unroll
    for (int dy = 0; dy < 2; ++dy)
#pragma unroll
      for (int nt = 0; nt < 2; ++nt) acc[dy][nt] = (floatx4){0.f, 0.f, 0.f, 0.f};

    for (int ks = 0; ks < KS; ++ks) {
      bhalf8 bf[2];
#pragma unroll
      for (int nt = 0; nt < 2; ++nt)
        bf[nt] = *(const bhalf8*)(bswz + ((size_t)(ks * 2 + nt) * 64 + lane) * 8);
      const int kk = ks * 32 + g * 8;
      const int tap = kk >> 4, icb = kk & 15;
      const int ky = tap >> 2, kx = tap & 3;
      bhalf8 af[2];
#pragma unroll
      for (int dy = 0; dy < 2; ++dy)
        af[dy] = *(const bhalf8*)&imgT[((2 * pyp + dy + ky) * IW + px + kx) * ROWU + icb];
#pragma unroll
      for (int dy = 0; dy < 2; ++dy)
#pragma unroll
        for (int nt = 0; nt < 2; ++nt)
          acc[dy][nt] = __builtin_amdgcn_mfma_f32_16x16x32_bf16(
              af[dy], bf[nt], acc[dy][nt], 0, 0, 0);
    }
#pragma unroll
    for (int nt = 0; nt < 2; ++nt) {
      const int oc = nt * 16 + col;
      const float bb = nt ? b1 : b0;
      float vv[4];
#pragma unroll
      for (int i = 0; i < 4; ++i) vv[i] = fmaxf(acc[0][nt][i], acc[1][nt][i]);
#pragma unroll
      for (int q = 0; q < 2; ++q) {
        const int pxp = tx * 8 + g * 2 + q;
        if (pxp < 22) {
          const float v = fmaxf(fmaxf(vv[2 * q], vv[2 * q + 1]) + bb, 0.f);
          out[((size_t)b * 32 + oc) * 484 + pyp * 22 + pxp] = v;
        }
      }
    }
  }
}

// ---------------- MFMA implicit-GEMM conv (+bias+relu) — unchanged PASS ----------------
template <int IC, int IH, int IW, int KW_, int OC, int MC>
__global__ __launch_bounds__(256) void convmfma_k(
    const float* __restrict__ in, const ushort* __restrict__ bswz,
    const float* __restrict__ bias, float* __restrict__ out)
{
  constexpr int OH = IH - KW_ + 1, OW = IW - KW_ + 1, P = OH * OW;
  constexpr int NPIX = IH * IW;
  constexpr int KS = IC * KW_ * KW_ / 32;
  constexpr int NT = OC / 16;
  constexpr int NPW = NT / 4;
  constexpr int MT = (P + 15) / 16;
  constexpr int ROWU = IC + 8;
  static_assert(NT % 4 == 0 && IC % 32 == 0, "cfg");

  __shared__ ushort imgT[NPIX * ROWU];
  const int b = blockIdx.x, tid = threadIdx.x;
  const int lane = tid & 63, wv = tid >> 6;
  const int icoff = (lane >> 4) * 8;

  for (int e = tid; e < IC * NPIX; e += 256) {
    const int ic = e / NPIX, pix = e % NPIX;
    imgT[pix * ROWU + ic] = f2bf(in[((size_t)b * IC + ic) * NPIX + pix]);
  }
  __syncthreads();

  for (int m0 = 0; m0 < MT; m0 += MC) {
    floatx4 acc[MC][NPW];
#pragma unroll
    for (int mi = 0; mi < MC; ++mi)
#pragma unroll
      for (int nn = 0; nn < NPW; ++nn)
        acc[mi][nn] = (floatx4){0.f, 0.f, 0.f, 0.f};

    int pbase[MC];
#pragma unroll
    for (int mi = 0; mi < MC; ++mi) {
      int p = (m0 + mi) * 16 + (lane & 15);
      p = p < P ? p : P - 1;
      pbase[mi] = ((p / OW) * IW + (p % OW)) * ROWU;
    }

    bhalf8 bcur[NPW];
#pragma unroll
    for (int nn = 0; nn < NPW; ++nn)
      bcur[nn] = *(const bhalf8*)(bswz + ((size_t)(wv * NPW + nn) * 64 + lane) * 8);

    for (int ks = 0; ks < KS; ++ks) {
      bhalf8 bnext[NPW];
      if (ks + 1 < KS) {
#pragma unroll
        for (int nn = 0; nn < NPW; ++nn)
          bnext[nn] = *(const bhalf8*)(bswz +
              ((size_t)((ks + 1) * NT + wv * NPW + nn) * 64 + lane) * 8);
      }
      const int tap = (ks * 32) / IC;
      const int icb = (ks * 32) % IC;
      const int aoff = ((tap / KW_) * IW + (tap % KW_)) * ROWU + icb + icoff;
      bhalf8 af[MC];
#pragma unroll
      for (int mi = 0; mi < MC; ++mi)
        af[mi] = *(const bhalf8*)&imgT[pbase[mi] + aoff];
#pragma unroll
      for (int mi = 0; mi < MC; ++mi)
#pragma unroll
        for (int nn = 0; nn < NPW; ++nn)
          acc[mi][nn] = __builtin_amdgcn_mfma_f32_16x16x32_bf16(
              af[mi], bcur[nn], acc[mi][nn], 0, 0, 0);
      if (ks + 1 < KS) {
#pragma unroll
        for (int nn = 0; nn < NPW; ++nn) bcur[nn] = bnext[nn];
      }
    }
#pragma unroll
    for (int mi = 0; mi < MC; ++mi)
#pragma unroll
      for (int nn = 0; nn < NPW; ++nn) {
        const int oc = (wv * NPW + nn) * 16 + (lane & 15);
#pragma unroll
        for (int i = 0; i < 4; ++i) {
          const int p = (m0 + mi) * 16 + (lane >> 4) * 4 + i;
          if (p < P) {
            const float v = fmaxf(acc[mi][nn][i] + bias[oc], 0.f);
            out[((size_t)b * OC + oc) * P + p] = v;
          }
        }
      }
  }
}

// ---------------- bf16 MFMA GEMM: C[M,N] = A[M,K] @ Bswz^T + bias ----------------
// BM=64, BN=64, BK=64, 256t/4 waves; wave -> 16 N-cols x 64 M-rows (4 M-tiles).
__global__ __launch_bounds__(256) void gemm_bf16_k(
    const ushort* __restrict__ abf, const ushort* __restrict__ bswz,
    const float* __restrict__ bias, float* __restrict__ C,
    int M, int N, int K)
{
  __shared__ ushort As[64][72];
  const int bn = blockIdx.x, bm = blockIdx.y, tid = threadIdx.x;
  const int lane = tid & 63, wv = tid >> 6;
  const int m0 = bm * 64, n0 = bn * 64;
  const int NTg = N / 16;
  const int ntg = bn * 4 + wv;
  floatx4 acc[4];
#pragma unroll
  for (int mt = 0; mt < 4; ++mt) acc[mt] = (floatx4){0.f, 0.f, 0.f, 0.f};

  for (int kc = 0; kc < K / 64; ++kc) {
    __syncthreads();
#pragma unroll
    for (int q = 0; q < 2; ++q) {
      const int id = q * 256 + tid;
      const int row = id >> 3, kcol = (id & 7) * 8;
      *(bhalf8*)&As[row][kcol] =
          *(const bhalf8*)&abf[(size_t)(m0 + row) * K + kc * 64 + kcol];
    }
    __syncthreads();
#pragma unroll
    for (int k2 = 0; k2 < 2; ++k2) {
      const int ks = kc * 2 + k2;
      const bhalf8 bf = *(const bhalf8*)(bswz + ((size_t)(ks * NTg + ntg) * 64 + lane) * 8);
      const int ksub = k2 * 32 + (lane >> 4) * 8;
#pragma unroll
      for (int mt = 0; mt < 4; ++mt) {
        const bhalf8 af = *(const bhalf8*)&As[mt * 16 + (lane & 15)][ksub];
        acc[mt] = __builtin_amdgcn_mfma_f32_16x16x32_bf16(af, bf, acc[mt], 0, 0, 0);
      }
    }
  }
  const int n = n0 + wv * 16 + (lane & 15);
  const float bb = bias[n];
#pragma unroll
  for (int mt = 0; mt < 4; ++mt)
#pragma unroll
    for (int i = 0; i < 4; ++i) {
      const int m = m0 + mt * 16 + (lane >> 4) * 4 + i;
      C[(size_t)m * N + n] = acc[mt][i] + bb;
    }
}

// ---------------- fp32 tiled GEMM (linear2, gin) — unchanged PASS ----------------
template <int ACT>
__global__ __launch_bounds__(256) void gemm_tn_k(
    const float* __restrict__ A, const float* __restrict__ B,
    const float* __restrict__ b1, const float* __restrict__ b2,
    float* __restrict__ C, int M, int N, int K)
{
  __shared__ float As[32][66];
  __shared__ float Bs[32][36];
  const int bn = blockIdx.x, bm = blockIdx.y, tid = threadIdx.x;
  const int tx = tid & 7, ty = tid >> 3;
  const int m0 = bm * 64, n0 = bn * 32;
  double acc[2][4] = {{0, 0, 0, 0}, {0, 0, 0, 0}};
  for (int k0 = 0; k0 < K; k0 += 32) {
    __syncthreads();
#pragma unroll
    for (int l = 0; l < 8; ++l) {
      int id = tid + l * 256;
      int kk = id & 31, mm = id >> 5;
      As[kk][mm] = A[(size_t)(m0 + mm) * K + (k0 + kk)];
    }
#pragma unroll
    for (int l = 0; l < 4; ++l) {
      int id = tid + l * 256;
      int kk = id & 31, nn = id >> 5;
      Bs[kk][nn] = B[(size_t)(n0 + nn) * K + (k0 + kk)];
    }
    __syncthreads();
    float p[2][4] = {{0.f, 0.f, 0.f, 0.f}, {0.f, 0.f, 0.f, 0.f}};
#pragma unroll
    for (int kk = 0; kk < 32; ++kk) {
      const float2 av = *reinterpret_cast<const float2*>(&As[kk][ty * 2]);
      const float4 bv = *reinterpret_cast<const float4*>(&Bs[kk][tx * 4]);
      p[0][0] += av.x * bv.x; p[0][1] += av.x * bv.y;
      p[0][2] += av.x * bv.z; p[0][3] += av.x * bv.w;
      p[1][0] += av.y * bv.x; p[1][1] += av.y * bv.y;
      p[1][2] += av.y * bv.z; p[1][3] += av.y * bv.w;
    }
#pragma unroll
    for (int i = 0; i < 2; ++i)
#pragma unroll
      for (int j = 0; j < 4; ++j) acc[i][j] += (double)p[i][j];
  }
#pragma unroll
  for (int i = 0; i < 2; ++i) {
    const int m = m0 + ty * 2 + i;
#pragma unroll
    for (int j = 0; j < 4; ++j) {
      const int n = n0 + tx * 4 + j;
      double v = acc[i][j] + (double)b1[n];
      if (b2) v += (double)b2[n];
      if (ACT == 1) v = 1.0 / (1.0 + exp(-v));
      C[(size_t)m * N + n] = (float)v;
    }
  }
}

// ---------------- persistent LSTM (R9: spin-on-data, no barrier/flags) ----------------
// h(t) published as ONE 8-byte relaxed agent atomic: (t+1)<<32 | bits(h).
// Consumers poll exactly the words they need; tag match => value valid
// (tag+payload atomic together). No fences, no flags, no global barrier;
// WGs self-synchronize via data (max skew 1 step). tagged[] zeroed per launch.
#define NWG 16
#define CPW 24
__global__ __launch_bounds__(768) void lstm_k(
    const float* __restrict__ gin, const float* __restrict__ whh,
    float* __restrict__ out, unsigned long long* __restrict__ tagged)
{
  __shared__ __align__(16) float hsm[8][52];
  __shared__ float gsum[96];
  const int wg = blockIdx.x, tid = threadIdx.x;
  const int r = tid >> 3, lk = tid & 7;
  const int gq = r / CPW, cl = r % CPW;
  const int grow = gq * 384 + wg * CPW + cl;
  float wreg[48];
  {
    const float* wr = whh + (size_t)grow * 384 + lk * 48;
#pragma unroll
    for (int i = 0; i < 48; ++i) wreg[i] = wr[i];
  }
  float c = 0.f;
  __syncthreads();
  for (int t = 0; t < 512; ++t) {
    float g0 = 0.f, g1 = 0.f, g2 = 0.f, g3 = 0.f;
    if (tid < CPW) {
      const int j = wg * CPW + tid;
      g0 = gin[(size_t)t * 1536 + 0 * 384 + j];
      g1 = gin[(size_t)t * 1536 + 1 * 384 + j];
      g2 = gin[(size_t)t * 1536 + 2 * 384 + j];
      g3 = gin[(size_t)t * 1536 + 3 * 384 + j];
    }
    if (tid < 384) {
      float hv;
      if (t == 0) {
        hv = 0.f;
      } else {
        unsigned long long u;
        do {
          u = __hip_atomic_load(&tagged[(size_t)(t - 1) * 384 + tid],
                                __ATOMIC_RELAXED, __HIP_MEMORY_SCOPE_AGENT);
        } while ((unsigned)(u >> 32) != (unsigned)t);
        union { unsigned ui; float f; } cv; cv.ui = (unsigned)u; hv = cv.f;
      }
      hsm[tid / 48][tid % 48] = hv;
    }
    __syncthreads();
    float s = 0.f;
    {
      const float4* hp = (const float4*)&hsm[lk][0];
#pragma unroll
      for (int q = 0; q < 12; ++q) {
        const float4 hv = hp[q];
        s += wreg[4 * q + 0] * hv.x + wreg[4 * q + 1] * hv.y
           + wreg[4 * q + 2] * hv.z + wreg[4 * q + 3] * hv.w;
      }
    }
    s += __shfl_xor(s, 1);
    s += __shfl_xor(s, 2);
    s += __shfl_xor(s, 4);
    if (lk == 0) gsum[r] = s;
    __syncthreads();
    if (tid < CPW) {
      const float gi = gsum[0 * CPW + tid] + g0;
      const float gf = gsum[1 * CPW + tid] + g1;
      const float gg = gsum[2 * CPW + tid] + g2;
      const float go = gsum[3 * CPW + tid] + g3;
      const float si = 1.f / (1.f + expf(-gi));
      const float sf = 1.f / (1.f + expf(-gf));
      const float so = 1.f / (1.f + expf(-go));
      c = sf * c + si * tanhf(gg);
      const float hn = so * tanhf(c);
      const int j = wg * CPW + tid;
      union { float f; unsigned ui; } cv; cv.f = hn;
      const unsigned long long pk = ((unsigned long long)(t + 1) << 32) | cv.ui;
      __hip_atomic_store(&tagged[(size_t)t * 384 + j], pk,
                         __ATOMIC_RELAXED, __HIP_MEMORY_SCOPE_AGENT);
      out[(size_t)t * 384 + j] = hn;
    }
    // no end-of-step barrier: next stage happens after producers' gates
    // (same thread), and the post-stage __syncthreads orders hsm/gsum reuse.
  }
}

extern "C" void kernel_launch(void* const* d_in, const int* in_sizes, int n_in,
                              void* d_out, int out_size, void* d_ws, size_t ws_size,
                              hipStream_t stream)
{
  const float* x   = (const float*)d_in[0];
  const float* cw1 = (const float*)d_in[1];
  const float* cb1 = (const float*)d_in[2];
  const float* cw2 = (const float*)d_in[3];
  const float* cb2 = (const float*)d_in[4];
  const float* cw3 = (const float*)d_in[5];
  const float* cb3 = (const float*)d_in[6];
  const float* cw4 = (const float*)d_in[7];
  const float* cb4 = (const float*)d_in[8];
  const float* cw5 = (const float*)d_in[9];
  const float* cb5 = (const float*)d_in[10];
  const float* cw6 = (const float*)d_in[11];
  const float* cb6 = (const float*)d_in[12];
  const float* lw1 = (const float*)d_in[13];
  const float* lb1 = (const float*)d_in[14];
  const float* lw2 = (const float*)d_in[15];
  const float* lb2 = (const float*)d_in[16];
  const float* wih = (const float*)d_in[17];
  const float* whh = (const float*)d_in[18];
  const float* bih = (const float*)d_in[19];
  const float* bhh = (const float*)d_in[20];
  float* out = (float*)d_out;
  char* ws = (char*)d_ws;

  // workspace layout (R3-fixed, proven; NO growth this round)
  float* bufA = (float*)(ws);                       // 72.4 MB conv ping
  float* bufB = (float*)(ws + 72384512);            // 51.4 MB conv pong
  float* l1o  = (float*)(ws + 123764736);           // 2 MB
  float* x2   = (float*)(ws + 125861888);
  float* gin  = (float*)(ws + 126648320);
  // conv bswz weights in l1o region (dead until linear1 output overwrites):
  ushort* bw3 = (ushort*)(ws + 123764736);
  ushort* bw4 = (ushort*)(ws + 123764736 + 102400);
  ushort* bw5 = (ushort*)(ws + 123764736 + 512000);
  ushort* bw6 = (ushort*)(ws + 123764736 + 1331200);
  ushort* bw2 = (ushort*)(ws + 123764736 + 1626112);
  // post-conv6 scratch inside then-dead bufA region:
  ushort* bw1 = (ushort*)(ws);                      // 16.8 MB swizzled lw1 bf16
  ushort* abf = (ushort*)(ws + 16777216);           // 8.4 MB conv6-out bf16
  unsigned long long* tagged = (unsigned long long*)(ws + 25165824);  // 1.57 MB

  // conv weight pre-swizzles (l1o region free until linear1)
  wprep_k<<<(25 * 4 * 64 + 255) / 256, 256, 0, stream>>>(cw3, bw3, 32, 5, 64, 25 * 4 * 64);
  wprep_k<<<(50 * 8 * 64 + 255) / 256, 256, 0, stream>>>(cw4, bw4, 64, 5, 128, 50 * 8 * 64);
  wprep_k<<<(100 * 8 * 64 + 255) / 256, 256, 0, stream>>>(cw5, bw5, 128, 5, 128, 100 * 8 * 64);
  wprep_k<<<(36 * 8 * 64 + 255) / 256, 256, 0, stream>>>(cw6, bw6, 128, 3, 128, 36 * 8 * 64);
  wprep_k<<<(8 * 2 * 64 + 255) / 256, 256, 0, stream>>>(cw2, bw2, 16, 4, 32, 8 * 2 * 64);

  conv1_pool_k<<<512, 256, 0, stream>>>(x, cw1, cb1, bufA);
  conv2mfma_k<<<512, 256, 0, stream>>>(bufA, bw2, cb2, bufB);
  convmfma_k<32, 22, 22, 5, 64, 7><<<512, 256, 0, stream>>>(bufB, bw3, cb3, bufA);
  convmfma_k<64, 18, 18, 5, 128, 7><<<512, 256, 0, stream>>>(bufA, bw4, cb4, bufB);
  convmfma_k<128, 14, 14, 5, 128, 7><<<512, 256, 0, stream>>>(bufB, bw5, cb5, bufA);
  convmfma_k<128, 10, 10, 3, 128, 4><<<512, 256, 0, stream>>>(bufA, bw6, cb6, bufB);
  // bufA now dead -> linear1 scratch + tagged live there
  wprep_lin_k<<<(256 * 64 * 64 + 255) / 256, 256, 0, stream>>>(lw1, bw1, 8192, 64, 256 * 64 * 64);
  f2bf_k<<<(512 * 8192 / 4 + 255) / 256, 256, 0, stream>>>(bufB, abf, 512 * 8192);
  hipMemsetAsync(tagged, 0, 512 * 384 * 8, stream);
  gemm_bf16_k<<<dim3(16, 8), 256, 0, stream>>>(abf, bw1, lb1, l1o, 512, 1024, 8192);
  gemm_tn_k<1><<<dim3(384 / 32, 512 / 64), 256, 0, stream>>>(l1o, lw2, lb2, nullptr, x2, 512, 384, 1024);
  gemm_tn_k<0><<<dim3(1536 / 32, 512 / 64), 256, 0, stream>>>(x2, wih, bih, bhh, gin, 512, 1536, 384);
  lstm_k<<<NWG, 768, 0, stream>>>(gin, whh, out, tagged);
}